// Round 5
// baseline (116.868 us; speedup 1.0000x reference)
//
#include <hip/hip_runtime.h>
#include <stdint.h>

#define BSZ 4096
#define LSEQ 1024

typedef short short8 __attribute__((ext_vector_type(8)));
typedef float f32x4 __attribute__((ext_vector_type(4)));

union S8 { int i[4]; short8 v; int4 q; };

__device__ __forceinline__ uint32_t pk_bf16x2(float a, float b) {
    uint32_t r;
    asm("v_cvt_pk_bf16_f32 %0, %1, %2" : "=v"(r) : "v"(a), "v"(b));
    return r;
}
// (a,b) -> hi dword [bf16(b)|bf16(a)], lo dword [bf16(b-bh)|bf16(a-ah)]
__device__ __forceinline__ void split_pair(float a, float b, int& dh, int& dl) {
    uint32_t h = pk_bf16x2(a, b);
    float ah = __uint_as_float(h << 16);
    float bh = __uint_as_float(h & 0xFFFF0000u);
    dh = (int)h;
    dl = (int)pk_bf16x2(a - ah, b - bh);
}
__device__ __forceinline__ float bf16hi(float a) {
    uint32_t h = pk_bf16x2(a, a);
    return __uint_as_float(h & 0xFFFF0000u);
}
__device__ __forceinline__ f32x4 MFMA(short8 a, short8 b, f32x4 c) {
    return __builtin_amdgcn_mfma_f32_16x16x32_bf16(a, b, c, 0, 0, 0);
}

// ws layout (int units):
//   int4 slots 0..13   : A fragments [f][lane]           (14*64*4 ints)
//   f32x4 slots 14..17 : bias1 C-frags [mt][lane]
//   f32x4 slots 18..19 : bias2 C-frags [mt2][lane]
//   f32x4 slot  20     : bias3 C-frag  [lane]
//   WS_EMBH + app      : pre-split embedding hi dword
//   WS_EMBL + app      : lo dword
//   WS_EMBR + i        : raw normalized embedding floats [10][2]
#define WS_EMBH 5376
#define WS_EMBL 5392
#define WS_EMBR 5408

__global__ void sp_prep(const float* __restrict__ emb,
                        const float* __restrict__ fW1, const float* __restrict__ fb1,
                        const float* __restrict__ fW2, const float* __restrict__ fb2,
                        const float* __restrict__ fW3, const float* __restrict__ fb3,
                        int* __restrict__ ws)
{
    const int lane = threadIdx.x;          // 64 threads, 1 wave
    const int L = lane & 15, g = lane >> 4;
    int4* wf = (int4*)ws;
    f32x4* bp = (f32x4*)ws;

    // ---- A1: single frag per mt, 3-term split packed along K (no bias row) ----
    // k slots 0-3: Ah (B=hi); 8-11: Ah (B=lo); 16-19: Al (B=hi); rest 0.
    #pragma unroll
    for (int mt = 0; mt < 4; ++mt) {
        int j1 = ((mt >> 1) << 5) + ((L >> 2) << 3) + ((mt & 1) << 2) + (L & 3);
        float v[8];
        #pragma unroll
        for (int e = 0; e < 8; ++e) {
            float src = (e < 4 && j1 < 50) ? fW1[e * 50 + j1] : 0.f;
            float hi = bf16hi(src);
            float lo = src - hi;
            v[e] = (g < 2) ? hi : (g == 2 ? lo : 0.f);
        }
        S8 F;
        #pragma unroll
        for (int d = 0; d < 4; ++d) F.i[d] = (int)pk_bf16x2(v[2*d], v[2*d+1]);
        wf[mt * 64 + lane] = F.q;
    }

    // ---- A2 hi/lo frags (sigma2 row permutation; no bias row) ----
    #pragma unroll
    for (int kt = 0; kt < 2; ++kt) {
        #pragma unroll
        for (int mt2 = 0; mt2 < 2; ++mt2) {
            int j2 = ((L >> 2) << 3) + (mt2 << 2) + (L & 3);
            float w[8];
            #pragma unroll
            for (int r = 0; r < 8; ++r) {
                int j1v = kt * 32 + 8 * g + r;
                w[r] = (j1v < 50 && j2 < 25) ? fW2[j1v * 25 + j2] : 0.f;
            }
            S8 H, Lo;
            #pragma unroll
            for (int d = 0; d < 4; ++d) split_pair(w[2*d], w[2*d+1], H.i[d], Lo.i[d]);
            wf[(4 + kt * 2 + mt2) * 64 + lane] = H.q;
            wf[(8 + kt * 2 + mt2) * 64 + lane] = Lo.q;
        }
    }

    // ---- A3 hi/lo frags (no bias row) ----
    {
        int m = L;
        float w[8];
        #pragma unroll
        for (int r = 0; r < 8; ++r) {
            int j2v = 8 * g + r;
            w[r] = (j2v < 25 && m < 5) ? fW3[j2v * 5 + m] : 0.f;
        }
        S8 H, Lo;
        #pragma unroll
        for (int d = 0; d < 4; ++d) split_pair(w[2*d], w[2*d+1], H.i[d], Lo.i[d]);
        wf[12 * 64 + lane] = H.q;
        wf[13 * 64 + lane] = Lo.q;
    }

    // ---- bias C-fragments (C/D row = 4g+r, col = L) ----
    #pragma unroll
    for (int mt = 0; mt < 4; ++mt) {
        f32x4 bv;
        #pragma unroll
        for (int r = 0; r < 4; ++r) {
            int j1 = ((mt >> 1) << 5) + 8 * g + ((mt & 1) << 2) + r;
            bv[r] = (j1 < 50) ? fb1[j1] : 0.f;
        }
        bp[(14 + mt) * 64 + lane] = bv;
    }
    #pragma unroll
    for (int mt2 = 0; mt2 < 2; ++mt2) {
        f32x4 bv;
        #pragma unroll
        for (int r = 0; r < 4; ++r) {
            int j2 = 8 * g + 4 * mt2 + r;
            bv[r] = (j2 < 25) ? fb2[j2] : 0.f;
        }
        bp[(18 + mt2) * 64 + lane] = bv;
    }
    {
        f32x4 bv;
        #pragma unroll
        for (int r = 0; r < 4; ++r) {
            int m = 4 * g + r;
            bv[r] = (m < 5) ? fb3[m] : 0.f;
        }
        bp[20 * 64 + lane] = bv;
    }

    // ---- renormalized embedding: raw floats + pre-split hi/lo dwords ----
    if (lane < 10) {
        float a0 = emb[2 * lane], a1 = emb[2 * lane + 1];
        float n = sqrtf(a0 * a0 + a1 * a1);
        float s = fminf(1.f, 1.f / fmaxf(n, 1e-7f));
        float e0 = a0 * s, e1 = a1 * s;
        int dh, dl;
        split_pair(e0, e1, dh, dl);
        ws[WS_EMBH + lane] = dh;
        ws[WS_EMBL + lane] = dl;
        ((float*)ws)[WS_EMBR + 2 * lane] = e0;
        ((float*)ws)[WS_EMBR + 2 * lane + 1] = e1;
    }
}

__global__ __launch_bounds__(256, 2) void sp_main(
    const float* __restrict__ x_features,
    const float* __restrict__ features,
    const int* __restrict__ ws,
    const float* __restrict__ rW1, const float* __restrict__ rb1,
    const float* __restrict__ rW2, const float* __restrict__ rb2,
    const float* __restrict__ rW3, const float* __restrict__ rb3,
    float* __restrict__ out)
{
    __shared__ int embh[16], embl[16];
    __shared__ float embr[20];
    __shared__ float redS[4][5], redM[4][5];
    __shared__ float hhs[14];
    __shared__ float r1buf[50];

    const int t = threadIdx.x;
    const int b = blockIdx.x;
    const int lane = t & 63;
    const int wid = t >> 6;
    const int L = lane & 15;
    const int g = lane >> 4;

    // ---- load prepacked A fragments + bias C-frags (L2-broadcast) ----
    const int4* wf = (const int4*)ws;
    const f32x4* bp = (const f32x4*)ws;
    S8 A1[4], A2H[4], A2L[4], A3H, A3L;
    #pragma unroll
    for (int f = 0; f < 4; ++f)  A1[f].q  = wf[f * 64 + lane];
    #pragma unroll
    for (int f = 0; f < 4; ++f)  A2H[f].q = wf[(4 + f) * 64 + lane];
    #pragma unroll
    for (int f = 0; f < 4; ++f)  A2L[f].q = wf[(8 + f) * 64 + lane];
    A3H.q = wf[12 * 64 + lane];
    A3L.q = wf[13 * 64 + lane];
    f32x4 b1c[4], b2c[2], b3c;
    #pragma unroll
    for (int f = 0; f < 4; ++f) b1c[f] = bp[(14 + f) * 64 + lane];
    b2c[0] = bp[18 * 64 + lane];
    b2c[1] = bp[19 * 64 + lane];
    b3c = bp[20 * 64 + lane];

    if (t < 16) { embh[t] = ws[WS_EMBH + t]; embl[t] = ws[WS_EMBL + t]; }
    if (t < 20) embr[t] = ((const float*)ws)[WS_EMBR + t];
    __syncthreads();

    const bool glo = (g == 1);
    const float* f0 = features + (size_t)b * (3 * LSEQ);
    const float* pa = f0;
    const float* pb = f0 + LSEQ;
    const float* pc = f0 + 2 * LSEQ;
    const int lbase = wid * 256 + L;

    float rs[4] = {0.f, 0.f, 0.f, 0.f};
    float rm[4] = {-3.4e38f, -3.4e38f, -3.4e38f, -3.4e38f};

    #pragma unroll 4
    for (int it = 0; it < 16; ++it) {
        const int l = lbase + it * 16;

        float fa  = pa[l];
        float l0v = pb[l];
        float l1v = pc[l];
        int app = (int)fa;
        int d0h = embh[app], d0l = embl[app];
        int d1h, d1l;
        split_pair(l0v, l1v, d1h, d1l);

        // B1: per-group hi/lo select (A masks the rest of K with zeros)
        S8 B1;
        B1.i[0] = glo ? d0l : d0h;
        B1.i[1] = glo ? d1l : d1h;
        B1.i[2] = 0;
        B1.i[3] = 0;

        // GEMM1: 4 MFMAs, bias in C
        f32x4 h1[4];
        #pragma unroll
        for (int mt = 0; mt < 4; ++mt)
            h1[mt] = MFMA(A1[mt].v, B1.v, b1c[mt]);
        #pragma unroll
        for (int mt = 0; mt < 4; ++mt) {
            h1[mt][0] = fmaxf(h1[mt][0], 0.f);
            h1[mt][1] = fmaxf(h1[mt][1], 0.f);
            h1[mt][2] = fmaxf(h1[mt][2], 0.f);
            h1[mt][3] = fmaxf(h1[mt][3], 0.f);
        }

        // B2 frags straight from registers (sigma1 alignment, verified r3/r4)
        S8 B2H0, B2L0, B2H1, B2L1;
        split_pair(h1[0][0], h1[0][1], B2H0.i[0], B2L0.i[0]);
        split_pair(h1[0][2], h1[0][3], B2H0.i[1], B2L0.i[1]);
        split_pair(h1[1][0], h1[1][1], B2H0.i[2], B2L0.i[2]);
        split_pair(h1[1][2], h1[1][3], B2H0.i[3], B2L0.i[3]);
        split_pair(h1[2][0], h1[2][1], B2H1.i[0], B2L1.i[0]);
        split_pair(h1[2][2], h1[2][3], B2H1.i[1], B2L1.i[1]);
        split_pair(h1[3][0], h1[3][1], B2H1.i[2], B2L1.i[2]);
        split_pair(h1[3][2], h1[3][3], B2H1.i[3], B2L1.i[3]);

        // GEMM2: 12 MFMAs, bias in C
        f32x4 h2[2];
        #pragma unroll
        for (int mt2 = 0; mt2 < 2; ++mt2) {
            f32x4 acc = b2c[mt2];
            acc = MFMA(A2H[0 * 2 + mt2].v, B2H0.v, acc);
            acc = MFMA(A2H[0 * 2 + mt2].v, B2L0.v, acc);
            acc = MFMA(A2L[0 * 2 + mt2].v, B2H0.v, acc);
            acc = MFMA(A2H[1 * 2 + mt2].v, B2H1.v, acc);
            acc = MFMA(A2H[1 * 2 + mt2].v, B2L1.v, acc);
            acc = MFMA(A2L[1 * 2 + mt2].v, B2H1.v, acc);
            h2[mt2] = acc;
        }
        #pragma unroll
        for (int mt2 = 0; mt2 < 2; ++mt2) {
            h2[mt2][0] = fmaxf(h2[mt2][0], 0.f);
            h2[mt2][1] = fmaxf(h2[mt2][1], 0.f);
            h2[mt2][2] = fmaxf(h2[mt2][2], 0.f);
            h2[mt2][3] = fmaxf(h2[mt2][3], 0.f);
        }

        // B3 frag
        S8 B3H, B3L;
        split_pair(h2[0][0], h2[0][1], B3H.i[0], B3L.i[0]);
        split_pair(h2[0][2], h2[0][3], B3H.i[1], B3L.i[1]);
        split_pair(h2[1][0], h2[1][1], B3H.i[2], B3L.i[2]);
        split_pair(h2[1][2], h2[1][3], B3H.i[3], B3L.i[3]);

        // GEMM3: 3 MFMAs, bias in C
        f32x4 h3 = b3c;
        h3 = MFMA(A3H.v, B3H.v, h3);
        h3 = MFMA(A3H.v, B3L.v, h3);
        h3 = MFMA(A3L.v, B3H.v, h3);

        #pragma unroll
        for (int r = 0; r < 4; ++r) {
            rs[r] += h3[r];
            rm[r] = fmaxf(rm[r], h3[r]);
        }
    }

    // ---- reduce over the 16 position-lanes within each 16-lane group ----
    #pragma unroll
    for (int off = 1; off <= 8; off <<= 1) {
        #pragma unroll
        for (int r = 0; r < 4; ++r) {
            rs[r] += __shfl_xor(rs[r], off);
            rm[r] = fmaxf(rm[r], __shfl_xor(rm[r], off));
        }
    }
    if (L == 0) {
        #pragma unroll
        for (int r = 0; r < 4; ++r) {
            int m = 4 * g + r;
            if (m < 5) { redS[wid][m] = rs[r]; redM[wid][m] = rm[r]; }
        }
    }
    __syncthreads();

    // ---- combine 4 waves + build hh[14] ----
    if (t < 5) {
        hhs[t] = (redS[0][t] + redS[1][t]) + (redS[2][t] + redS[3][t]);
    } else if (t < 10) {
        int m = t - 5;
        hhs[t] = fmaxf(fmaxf(redM[0][m], redM[1][m]), fmaxf(redM[2][m], redM[3][m]));
    } else if (t == 10) {
        int xa = (int)x_features[b * 3];
        hhs[10] = embr[2 * xa];
        hhs[11] = embr[2 * xa + 1];
        hhs[12] = x_features[b * 3 + 1];
        hhs[13] = x_features[b * 3 + 2];
    }
    __syncthreads();

    // ---- head MLP: 14 -> 50 -> 25 -> 1 (weights direct from L2) ----
    if (t < 50) {
        float acc = rb1[t];
        #pragma unroll
        for (int i = 0; i < 14; ++i) acc += hhs[i] * rW1[i * 50 + t];
        r1buf[t] = fmaxf(acc, 0.f);
    }
    __syncthreads();

    float oacc = 0.f;
    if (t < 25) {
        float acc = rb2[t];
        #pragma unroll
        for (int k = 0; k < 50; ++k) acc += r1buf[k] * rW2[k * 25 + t];
        oacc = fmaxf(acc, 0.f) * rW3[t];
    }
    if (t < 64) {
        #pragma unroll
        for (int off = 32; off > 0; off >>= 1) oacc += __shfl_down(oacc, off);
        if (t == 0) out[b] = oacc + rb3[0];
    }
}

extern "C" void kernel_launch(void* const* d_in, const int* in_sizes, int n_in,
                              void* d_out, int out_size, void* d_ws, size_t ws_size,
                              hipStream_t stream) {
    const float* x_features = (const float*)d_in[0];
    const float* features   = (const float*)d_in[1];
    // d_in[2] = lengths (dead in the math)
    const float* emb = (const float*)d_in[3];
    const float* fW1 = (const float*)d_in[4];
    const float* fb1 = (const float*)d_in[5];
    const float* fW2 = (const float*)d_in[6];
    const float* fb2 = (const float*)d_in[7];
    const float* fW3 = (const float*)d_in[8];
    const float* fb3 = (const float*)d_in[9];
    const float* rW1 = (const float*)d_in[10];
    const float* rb1 = (const float*)d_in[11];
    const float* rW2 = (const float*)d_in[12];
    const float* rb2 = (const float*)d_in[13];
    const float* rW3 = (const float*)d_in[14];
    const float* rb3 = (const float*)d_in[15];
    float* out = (float*)d_out;
    int* ws = (int*)d_ws;

    sp_prep<<<1, 64, 0, stream>>>(emb, fW1, fb1, fW2, fb2, fW3, fb3, ws);
    sp_main<<<BSZ, 256, 0, stream>>>(x_features, features, ws,
                                     rW1, rb1, rW2, rb2, rW3, rb3, out);
}

// Round 6
// 104.595 us; speedup vs baseline: 1.1173x; 1.1173x over previous
//
#include <hip/hip_runtime.h>
#include <stdint.h>

#define BSZ 4096
#define LSEQ 1024

typedef short short8 __attribute__((ext_vector_type(8)));
typedef float f32x4 __attribute__((ext_vector_type(4)));

union S8 { int i[4]; short8 v; int4 q; };

__device__ __forceinline__ uint32_t pk_bf16x2(float a, float b) {
    uint32_t r;
    asm("v_cvt_pk_bf16_f32 %0, %1, %2" : "=v"(r) : "v"(a), "v"(b));
    return r;
}
// (a,b) -> hi dword [bf16(b)|bf16(a)], lo dword [bf16(b-bh)|bf16(a-ah)]
__device__ __forceinline__ void split_pair(float a, float b, int& dh, int& dl) {
    uint32_t h = pk_bf16x2(a, b);
    float ah = __uint_as_float(h << 16);
    float bh = __uint_as_float(h & 0xFFFF0000u);
    dh = (int)h;
    dl = (int)pk_bf16x2(a - ah, b - bh);
}
__device__ __forceinline__ float bf16hi(float a) {
    uint32_t h = pk_bf16x2(a, a);
    return __uint_as_float(h & 0xFFFF0000u);
}
__device__ __forceinline__ f32x4 MFMA(short8 a, short8 b, f32x4 c) {
    return __builtin_amdgcn_mfma_f32_16x16x32_bf16(a, b, c, 0, 0, 0);
}

// ws layout (int units):
//   int4 slots 0..13   : A fragments [f][lane]           (14*64*4 ints)
//   f32x4 slots 14..17 : bias1 C-frags [mt][lane]
//   f32x4 slots 18..19 : bias2 C-frags [mt2][lane]
//   f32x4 slot  20     : bias3 C-frag  [lane]
//   WS_EMBH + app      : pre-split embedding hi dword
//   WS_EMBL + app      : lo dword
//   WS_EMBR + i        : raw normalized embedding floats [10][2]
#define WS_EMBH 5376
#define WS_EMBL 5392
#define WS_EMBR 5408

__global__ void sp_prep(const float* __restrict__ emb,
                        const float* __restrict__ fW1, const float* __restrict__ fb1,
                        const float* __restrict__ fW2, const float* __restrict__ fb2,
                        const float* __restrict__ fW3, const float* __restrict__ fb3,
                        int* __restrict__ ws)
{
    const int lane = threadIdx.x;          // 64 threads, 1 wave
    const int L = lane & 15, g = lane >> 4;
    int4* wf = (int4*)ws;
    f32x4* bp = (f32x4*)ws;

    // ---- A1: single frag per mt, 3-term split packed along K (no bias row) ----
    // k slots 0-3: Ah (B=hi); 8-11: Ah (B=lo); 16-19: Al (B=hi); rest 0.
    #pragma unroll
    for (int mt = 0; mt < 4; ++mt) {
        int j1 = ((mt >> 1) << 5) + ((L >> 2) << 3) + ((mt & 1) << 2) + (L & 3);
        float v[8];
        #pragma unroll
        for (int e = 0; e < 8; ++e) {
            float src = (e < 4 && j1 < 50) ? fW1[e * 50 + j1] : 0.f;
            float hi = bf16hi(src);
            float lo = src - hi;
            v[e] = (g < 2) ? hi : (g == 2 ? lo : 0.f);
        }
        S8 F;
        #pragma unroll
        for (int d = 0; d < 4; ++d) F.i[d] = (int)pk_bf16x2(v[2*d], v[2*d+1]);
        wf[mt * 64 + lane] = F.q;
    }

    // ---- A2 hi/lo frags (sigma2 row permutation; no bias row) ----
    #pragma unroll
    for (int kt = 0; kt < 2; ++kt) {
        #pragma unroll
        for (int mt2 = 0; mt2 < 2; ++mt2) {
            int j2 = ((L >> 2) << 3) + (mt2 << 2) + (L & 3);
            float w[8];
            #pragma unroll
            for (int r = 0; r < 8; ++r) {
                int j1v = kt * 32 + 8 * g + r;
                w[r] = (j1v < 50 && j2 < 25) ? fW2[j1v * 25 + j2] : 0.f;
            }
            S8 H, Lo;
            #pragma unroll
            for (int d = 0; d < 4; ++d) split_pair(w[2*d], w[2*d+1], H.i[d], Lo.i[d]);
            wf[(4 + kt * 2 + mt2) * 64 + lane] = H.q;
            wf[(8 + kt * 2 + mt2) * 64 + lane] = Lo.q;
        }
    }

    // ---- A3 hi/lo frags (no bias row) ----
    {
        int m = L;
        float w[8];
        #pragma unroll
        for (int r = 0; r < 8; ++r) {
            int j2v = 8 * g + r;
            w[r] = (j2v < 25 && m < 5) ? fW3[j2v * 5 + m] : 0.f;
        }
        S8 H, Lo;
        #pragma unroll
        for (int d = 0; d < 4; ++d) split_pair(w[2*d], w[2*d+1], H.i[d], Lo.i[d]);
        wf[12 * 64 + lane] = H.q;
        wf[13 * 64 + lane] = Lo.q;
    }

    // ---- bias C-fragments (C/D row = 4g+r, col = L) ----
    #pragma unroll
    for (int mt = 0; mt < 4; ++mt) {
        f32x4 bv;
        #pragma unroll
        for (int r = 0; r < 4; ++r) {
            int j1 = ((mt >> 1) << 5) + 8 * g + ((mt & 1) << 2) + r;
            bv[r] = (j1 < 50) ? fb1[j1] : 0.f;
        }
        bp[(14 + mt) * 64 + lane] = bv;
    }
    #pragma unroll
    for (int mt2 = 0; mt2 < 2; ++mt2) {
        f32x4 bv;
        #pragma unroll
        for (int r = 0; r < 4; ++r) {
            int j2 = 8 * g + 4 * mt2 + r;
            bv[r] = (j2 < 25) ? fb2[j2] : 0.f;
        }
        bp[(18 + mt2) * 64 + lane] = bv;
    }
    {
        f32x4 bv;
        #pragma unroll
        for (int r = 0; r < 4; ++r) {
            int m = 4 * g + r;
            bv[r] = (m < 5) ? fb3[m] : 0.f;
        }
        bp[20 * 64 + lane] = bv;
    }

    // ---- renormalized embedding: raw floats + pre-split hi/lo dwords ----
    if (lane < 10) {
        float a0 = emb[2 * lane], a1 = emb[2 * lane + 1];
        float n = sqrtf(a0 * a0 + a1 * a1);
        float s = fminf(1.f, 1.f / fmaxf(n, 1e-7f));
        float e0 = a0 * s, e1 = a1 * s;
        int dh, dl;
        split_pair(e0, e1, dh, dl);
        ws[WS_EMBH + lane] = dh;
        ws[WS_EMBL + lane] = dl;
        ((float*)ws)[WS_EMBR + 2 * lane] = e0;
        ((float*)ws)[WS_EMBR + 2 * lane + 1] = e1;
    }
}

__global__ __launch_bounds__(256, 3) void sp_main(
    const float* __restrict__ x_features,
    const float* __restrict__ features,
    const int* __restrict__ ws,
    const float* __restrict__ rW1, const float* __restrict__ rb1,
    const float* __restrict__ rW2, const float* __restrict__ rb2,
    const float* __restrict__ rW3, const float* __restrict__ rb3,
    float* __restrict__ out)
{
    __shared__ int2 embhl[16];
    __shared__ float embr[20];
    __shared__ float redS[4][5], redM[4][5];
    __shared__ float hhs[14];
    __shared__ float r1buf[50];

    const int t = threadIdx.x;
    const int b = blockIdx.x;
    const int lane = t & 63;
    const int wid = t >> 6;
    const int L = lane & 15;
    const int g = lane >> 4;

    // ---- load prepacked A fragments + bias C-frags (L2-broadcast) ----
    const int4* wf = (const int4*)ws;
    const f32x4* bp = (const f32x4*)ws;
    S8 A1[4], A2H[4], A2L[4], A3H, A3L;
    #pragma unroll
    for (int f = 0; f < 4; ++f)  A1[f].q  = wf[f * 64 + lane];
    #pragma unroll
    for (int f = 0; f < 4; ++f)  A2H[f].q = wf[(4 + f) * 64 + lane];
    #pragma unroll
    for (int f = 0; f < 4; ++f)  A2L[f].q = wf[(8 + f) * 64 + lane];
    A3H.q = wf[12 * 64 + lane];
    A3L.q = wf[13 * 64 + lane];
    f32x4 b1c[4], b2c[2], b3c;
    #pragma unroll
    for (int f = 0; f < 4; ++f) b1c[f] = bp[(14 + f) * 64 + lane];
    b2c[0] = bp[18 * 64 + lane];
    b2c[1] = bp[19 * 64 + lane];
    b3c = bp[20 * 64 + lane];

    if (t < 16) { embhl[t] = make_int2(ws[WS_EMBH + t], ws[WS_EMBL + t]); }
    if (t < 20) embr[t] = ((const float*)ws)[WS_EMBR + t];
    __syncthreads();

    const bool glo = (g == 1);
    const float* f0 = features + (size_t)b * (3 * LSEQ);

    float rs[4] = {0.f, 0.f, 0.f, 0.f};
    float rm[4] = {-3.4e38f, -3.4e38f, -3.4e38f, -3.4e38f};

    #pragma unroll 2
    for (int it = 0; it < 16; ++it) {
        const int l = (wid * 16 + it) * 16 + L;

        float fa  = f0[l];
        float l0v = f0[LSEQ + l];
        float l1v = f0[2 * LSEQ + l];
        int app = (int)fa;
        int2 ehl = embhl[app];              // one ds_read_b64
        int d1h, d1l;
        split_pair(l0v, l1v, d1h, d1l);

        // B1: per-group hi/lo select (A masks the rest of K with zeros)
        S8 B1;
        B1.i[0] = glo ? ehl.y : ehl.x;
        B1.i[1] = glo ? d1l : d1h;
        B1.i[2] = 0;
        B1.i[3] = 0;

        // GEMM1: 4 independent MFMAs, bias in C
        f32x4 h1[4];
        #pragma unroll
        for (int mt = 0; mt < 4; ++mt)
            h1[mt] = MFMA(A1[mt].v, B1.v, b1c[mt]);
        #pragma unroll
        for (int mt = 0; mt < 4; ++mt) {
            h1[mt][0] = fmaxf(h1[mt][0], 0.f);
            h1[mt][1] = fmaxf(h1[mt][1], 0.f);
            h1[mt][2] = fmaxf(h1[mt][2], 0.f);
            h1[mt][3] = fmaxf(h1[mt][3], 0.f);
        }

        // B2 frags straight from registers (sigma1 alignment, verified r3/r4)
        S8 B2H0, B2L0, B2H1, B2L1;
        split_pair(h1[0][0], h1[0][1], B2H0.i[0], B2L0.i[0]);
        split_pair(h1[0][2], h1[0][3], B2H0.i[1], B2L0.i[1]);
        split_pair(h1[1][0], h1[1][1], B2H0.i[2], B2L0.i[2]);
        split_pair(h1[1][2], h1[1][3], B2H0.i[3], B2L0.i[3]);
        split_pair(h1[2][0], h1[2][1], B2H1.i[0], B2L1.i[0]);
        split_pair(h1[2][2], h1[2][3], B2H1.i[1], B2L1.i[1]);
        split_pair(h1[3][0], h1[3][1], B2H1.i[2], B2L1.i[2]);
        split_pair(h1[3][2], h1[3][3], B2H1.i[3], B2L1.i[3]);

        // GEMM2: 12 MFMAs as 4 independent 3-chains (2 per mt2), bias in accA
        f32x4 h2[2];
        #pragma unroll
        for (int mt2 = 0; mt2 < 2; ++mt2) {
            f32x4 accA = b2c[mt2];
            accA = MFMA(A2H[mt2].v, B2H0.v, accA);        // kt0 HH
            accA = MFMA(A2H[mt2].v, B2L0.v, accA);        // kt0 HL
            accA = MFMA(A2L[mt2].v, B2H0.v, accA);        // kt0 LH
            f32x4 accB = {0.f, 0.f, 0.f, 0.f};
            accB = MFMA(A2H[2 + mt2].v, B2H1.v, accB);    // kt1 HH
            accB = MFMA(A2H[2 + mt2].v, B2L1.v, accB);    // kt1 HL
            accB = MFMA(A2L[2 + mt2].v, B2H1.v, accB);    // kt1 LH
            h2[mt2] = accA + accB;
        }
        #pragma unroll
        for (int mt2 = 0; mt2 < 2; ++mt2) {
            h2[mt2][0] = fmaxf(h2[mt2][0], 0.f);
            h2[mt2][1] = fmaxf(h2[mt2][1], 0.f);
            h2[mt2][2] = fmaxf(h2[mt2][2], 0.f);
            h2[mt2][3] = fmaxf(h2[mt2][3], 0.f);
        }

        // B3 frag
        S8 B3H, B3L;
        split_pair(h2[0][0], h2[0][1], B3H.i[0], B3L.i[0]);
        split_pair(h2[0][2], h2[0][3], B3H.i[1], B3L.i[1]);
        split_pair(h2[1][0], h2[1][1], B3H.i[2], B3L.i[2]);
        split_pair(h2[1][2], h2[1][3], B3H.i[3], B3L.i[3]);

        // GEMM3: 3 MFMAs as 2 independent chains, bias in chain A
        f32x4 g3a = b3c;
        g3a = MFMA(A3H.v, B3H.v, g3a);
        g3a = MFMA(A3L.v, B3H.v, g3a);
        f32x4 g3b = {0.f, 0.f, 0.f, 0.f};
        g3b = MFMA(A3H.v, B3L.v, g3b);
        f32x4 h3 = g3a + g3b;

        #pragma unroll
        for (int r = 0; r < 4; ++r) {
            rs[r] += h3[r];
            rm[r] = fmaxf(rm[r], h3[r]);
        }
    }

    // ---- reduce over the 16 position-lanes within each 16-lane group ----
    #pragma unroll
    for (int off = 1; off <= 8; off <<= 1) {
        #pragma unroll
        for (int r = 0; r < 4; ++r) {
            rs[r] += __shfl_xor(rs[r], off);
            rm[r] = fmaxf(rm[r], __shfl_xor(rm[r], off));
        }
    }
    if (L == 0) {
        #pragma unroll
        for (int r = 0; r < 4; ++r) {
            int m = 4 * g + r;
            if (m < 5) { redS[wid][m] = rs[r]; redM[wid][m] = rm[r]; }
        }
    }
    __syncthreads();

    // ---- combine 4 waves + build hh[14] ----
    if (t < 5) {
        hhs[t] = (redS[0][t] + redS[1][t]) + (redS[2][t] + redS[3][t]);
    } else if (t < 10) {
        int m = t - 5;
        hhs[t] = fmaxf(fmaxf(redM[0][m], redM[1][m]), fmaxf(redM[2][m], redM[3][m]));
    } else if (t == 10) {
        int xa = (int)x_features[b * 3];
        hhs[10] = embr[2 * xa];
        hhs[11] = embr[2 * xa + 1];
        hhs[12] = x_features[b * 3 + 1];
        hhs[13] = x_features[b * 3 + 2];
    }
    __syncthreads();

    // ---- head MLP: 14 -> 50 -> 25 -> 1 (weights direct from L2) ----
    if (t < 50) {
        float acc = rb1[t];
        #pragma unroll
        for (int i = 0; i < 14; ++i) acc += hhs[i] * rW1[i * 50 + t];
        r1buf[t] = fmaxf(acc, 0.f);
    }
    __syncthreads();

    float oacc = 0.f;
    if (t < 25) {
        float acc = rb2[t];
        #pragma unroll
        for (int k = 0; k < 50; ++k) acc += r1buf[k] * rW2[k * 25 + t];
        oacc = fmaxf(acc, 0.f) * rW3[t];
    }
    if (t < 64) {
        #pragma unroll
        for (int off = 32; off > 0; off >>= 1) oacc += __shfl_down(oacc, off);
        if (t == 0) out[b] = oacc + rb3[0];
    }
}

extern "C" void kernel_launch(void* const* d_in, const int* in_sizes, int n_in,
                              void* d_out, int out_size, void* d_ws, size_t ws_size,
                              hipStream_t stream) {
    const float* x_features = (const float*)d_in[0];
    const float* features   = (const float*)d_in[1];
    // d_in[2] = lengths (dead in the math)
    const float* emb = (const float*)d_in[3];
    const float* fW1 = (const float*)d_in[4];
    const float* fb1 = (const float*)d_in[5];
    const float* fW2 = (const float*)d_in[6];
    const float* fb2 = (const float*)d_in[7];
    const float* fW3 = (const float*)d_in[8];
    const float* fb3 = (const float*)d_in[9];
    const float* rW1 = (const float*)d_in[10];
    const float* rb1 = (const float*)d_in[11];
    const float* rW2 = (const float*)d_in[12];
    const float* rb2 = (const float*)d_in[13];
    const float* rW3 = (const float*)d_in[14];
    const float* rb3 = (const float*)d_in[15];
    float* out = (float*)d_out;
    int* ws = (int*)d_ws;

    sp_prep<<<1, 64, 0, stream>>>(emb, fW1, fb1, fW2, fb2, fW3, fb3, ws);
    sp_main<<<BSZ, 256, 0, stream>>>(x_features, features, ws,
                                     rW1, rb1, rW2, rb2, rW3, rb3, out);
}

// Round 7
// 85.936 us; speedup vs baseline: 1.3600x; 1.2171x over previous
//
#include <hip/hip_runtime.h>
#include <stdint.h>

#define BSZ 4096
#define LSEQ 1024

typedef _Float16 half8 __attribute__((ext_vector_type(8)));
typedef float f32x4 __attribute__((ext_vector_type(4)));

union S8 { int i[4]; half8 h; int4 q; };

__device__ __forceinline__ int pack_f16(float a, float b) {
    union { _Float16 h[2]; int i; } u;
    u.h[0] = (_Float16)a;          // v_cvt_f16_f32 (RNE)
    u.h[1] = (_Float16)b;
    return u.i;                    // v_pack_b32_f16
}
// (a,b) -> hi dword [f16(b)|f16(a)], lo dword [f16(b-bh)|f16(a-ah)]
__device__ __forceinline__ void split_pair_f16(float a, float b, int& dh, int& dl) {
    _Float16 ah = (_Float16)a, bh = (_Float16)b;
    float al = a - (float)ah, bl = b - (float)bh;
    union { _Float16 h[2]; int i; } uh, ul;
    uh.h[0] = ah; uh.h[1] = bh;
    ul.h[0] = (_Float16)al; ul.h[1] = (_Float16)bl;
    dh = uh.i; dl = ul.i;
}
__device__ __forceinline__ f32x4 MFMA(half8 a, half8 b, f32x4 c) {
    return __builtin_amdgcn_mfma_f32_16x16x32_f16(a, b, c, 0, 0, 0);
}

// ws layout (int units):
//   int4 slots 0..13   : A fragments [f][lane]   (14*64*4 = 3584 ints)
//   f32x4 slots 14..17 : bias1 C-frags [mt][lane]
//   f32x4 slots 18..19 : bias2 C-frags [mt2][lane]
//   f32x4 slot  20     : bias3 C-frag  [lane]
//   WS_EMBH + app      : embedding hi dword (f16 e0,e1)
//   WS_EMBL + app      : embedding lo dword
//   WS_EMBR + i        : raw normalized embedding floats [10][2]
#define WS_EMBH 5376
#define WS_EMBL 5392
#define WS_EMBR 5408

__global__ void sp_prep(const float* __restrict__ emb,
                        const float* __restrict__ fW1, const float* __restrict__ fb1,
                        const float* __restrict__ fW2, const float* __restrict__ fb2,
                        const float* __restrict__ fW3, const float* __restrict__ fb3,
                        int* __restrict__ ws)
{
    const int lane = threadIdx.x;          // 64 threads, 1 wave
    const int L = lane & 15, g = lane >> 4;
    int4* wf = (int4*)ws;
    f32x4* bp = (f32x4*)ws;

    // ---- A1: one frag per mt; A 2-term f16 packed along K ----
    // B1 supplies per lane-group g in {0,1}: [d_eh, d_l, d_el, 0]
    // k slots (k=8g+e): g0: e0..3 = Ah(cols e0,e1,l0,l1), e4..5 = Ah(We cols) (pairs e-lo)
    //                   g1: e0..3 = Al(cols),              e4..5 = Al(We cols)
    #pragma unroll
    for (int mt = 0; mt < 4; ++mt) {
        int j1 = ((mt >> 1) << 5) + ((L >> 2) << 3) + ((mt & 1) << 2) + (L & 3);
        float wv[4];
        _Float16 ah[4]; float alv[4];
        #pragma unroll
        for (int c = 0; c < 4; ++c) {
            wv[c] = (j1 < 50) ? fW1[c * 50 + j1] : 0.f;
            ah[c] = (_Float16)wv[c];
            alv[c] = wv[c] - (float)ah[c];
        }
        _Float16 v[8];
        #pragma unroll
        for (int e = 0; e < 8; ++e) {
            _Float16 x = (_Float16)0.f;
            if (g == 0) {
                if (e < 4) x = ah[e];
                else if (e < 6) x = ah[e - 4];
            } else if (g == 1) {
                if (e < 4) x = (_Float16)alv[e];
                else if (e < 6) x = (_Float16)alv[e - 4];
            }
            v[e] = x;
        }
        S8 F;
        #pragma unroll
        for (int d = 0; d < 4; ++d) {
            union { _Float16 h[2]; int i; } u;
            u.h[0] = v[2 * d]; u.h[1] = v[2 * d + 1];
            F.i[d] = u.i;
        }
        wf[mt * 64 + lane] = F.q;
    }

    // ---- A2 Ah/Al frags (sigma2 row permutation; f16 2-term) ----
    #pragma unroll
    for (int kt = 0; kt < 2; ++kt) {
        #pragma unroll
        for (int mt2 = 0; mt2 < 2; ++mt2) {
            int j2 = ((L >> 2) << 3) + (mt2 << 2) + (L & 3);
            float w[8];
            #pragma unroll
            for (int r = 0; r < 8; ++r) {
                int j1v = kt * 32 + 8 * g + r;
                w[r] = (j1v < 50 && j2 < 25) ? fW2[j1v * 25 + j2] : 0.f;
            }
            S8 H, Lo;
            #pragma unroll
            for (int d = 0; d < 4; ++d) split_pair_f16(w[2*d], w[2*d+1], H.i[d], Lo.i[d]);
            wf[(4 + kt * 2 + mt2) * 64 + lane] = H.q;
            wf[(8 + kt * 2 + mt2) * 64 + lane] = Lo.q;
        }
    }

    // ---- A3 Ah/Al frags ----
    {
        int m = L;
        float w[8];
        #pragma unroll
        for (int r = 0; r < 8; ++r) {
            int j2v = 8 * g + r;
            w[r] = (j2v < 25 && m < 5) ? fW3[j2v * 5 + m] : 0.f;
        }
        S8 H, Lo;
        #pragma unroll
        for (int d = 0; d < 4; ++d) split_pair_f16(w[2*d], w[2*d+1], H.i[d], Lo.i[d]);
        wf[12 * 64 + lane] = H.q;
        wf[13 * 64 + lane] = Lo.q;
    }

    // ---- bias C-fragments (C/D row = 4g+r, col = L) ----
    #pragma unroll
    for (int mt = 0; mt < 4; ++mt) {
        f32x4 bv;
        #pragma unroll
        for (int r = 0; r < 4; ++r) {
            int j1 = ((mt >> 1) << 5) + 8 * g + ((mt & 1) << 2) + r;
            bv[r] = (j1 < 50) ? fb1[j1] : 0.f;
        }
        bp[(14 + mt) * 64 + lane] = bv;
    }
    #pragma unroll
    for (int mt2 = 0; mt2 < 2; ++mt2) {
        f32x4 bv;
        #pragma unroll
        for (int r = 0; r < 4; ++r) {
            int j2 = 8 * g + 4 * mt2 + r;
            bv[r] = (j2 < 25) ? fb2[j2] : 0.f;
        }
        bp[(18 + mt2) * 64 + lane] = bv;
    }
    {
        f32x4 bv;
        #pragma unroll
        for (int r = 0; r < 4; ++r) {
            int m = 4 * g + r;
            bv[r] = (m < 5) ? fb3[m] : 0.f;
        }
        bp[20 * 64 + lane] = bv;
    }

    // ---- renormalized embedding: raw floats + f16 hi/lo dwords ----
    if (lane < 10) {
        float a0 = emb[2 * lane], a1 = emb[2 * lane + 1];
        float n = sqrtf(a0 * a0 + a1 * a1);
        float s = fminf(1.f, 1.f / fmaxf(n, 1e-7f));
        float e0 = a0 * s, e1 = a1 * s;
        int dh, dl;
        split_pair_f16(e0, e1, dh, dl);
        ws[WS_EMBH + lane] = dh;
        ws[WS_EMBL + lane] = dl;
        ((float*)ws)[WS_EMBR + 2 * lane] = e0;
        ((float*)ws)[WS_EMBR + 2 * lane + 1] = e1;
    }
}

__global__ __launch_bounds__(256, 3) void sp_main(
    const float* __restrict__ x_features,
    const float* __restrict__ features,
    const int* __restrict__ ws,
    const float* __restrict__ rW1, const float* __restrict__ rb1,
    const float* __restrict__ rW2, const float* __restrict__ rb2,
    const float* __restrict__ rW3, const float* __restrict__ rb3,
    float* __restrict__ out)
{
    __shared__ int2 embhl[16];
    __shared__ float embr[20];
    __shared__ float redS[4][5], redM[4][5];
    __shared__ float hhs[14];
    __shared__ float r1buf[50];

    const int t = threadIdx.x;
    const int b = blockIdx.x;
    const int lane = t & 63;
    const int wid = t >> 6;
    const int L = lane & 15;
    const int g = lane >> 4;

    // ---- load prepacked A fragments + bias C-frags (L2-broadcast) ----
    const int4* wf = (const int4*)ws;
    const f32x4* bp = (const f32x4*)ws;
    S8 A1[4], A2H[4], A2L[4], A3H, A3L;
    #pragma unroll
    for (int f = 0; f < 4; ++f)  A1[f].q  = wf[f * 64 + lane];
    #pragma unroll
    for (int f = 0; f < 4; ++f)  A2H[f].q = wf[(4 + f) * 64 + lane];
    #pragma unroll
    for (int f = 0; f < 4; ++f)  A2L[f].q = wf[(8 + f) * 64 + lane];
    A3H.q = wf[12 * 64 + lane];
    A3L.q = wf[13 * 64 + lane];
    f32x4 b1c[4], b2c[2], b3c;
    #pragma unroll
    for (int f = 0; f < 4; ++f) b1c[f] = bp[(14 + f) * 64 + lane];
    b2c[0] = bp[18 * 64 + lane];
    b2c[1] = bp[19 * 64 + lane];
    b3c = bp[20 * 64 + lane];

    if (t < 16) { embhl[t] = make_int2(ws[WS_EMBH + t], ws[WS_EMBL + t]); }
    if (t < 20) embr[t] = ((const float*)ws)[WS_EMBR + t];
    __syncthreads();

    const bool bact = (g < 2);
    const float* f0 = features + (size_t)b * (3 * LSEQ);
    const float* pa = f0;
    const float* pb = f0 + LSEQ;
    const float* pc = f0 + 2 * LSEQ;
    const int lbase = wid * 256 + L;

    float rs[4] = {0.f, 0.f, 0.f, 0.f};
    float rm[4] = {-3.4e38f, -3.4e38f, -3.4e38f, -3.4e38f};

    // software-pipelined input stream (prefetch next tile's 3 floats)
    float fa = pa[lbase], v0 = pb[lbase], v1 = pc[lbase];

    #pragma unroll 2
    for (int it = 0; it < 16; ++it) {
        const int ln = lbase + ((it + 1) & 15) * 16;   // wraps on last iter (in-bounds)
        float nfa = pa[ln], nv0 = pb[ln], nv1 = pc[ln];

        int app = (int)fa;
        int2 ehl = embhl[app];                         // one ds_read_b64
        int d_l = pack_f16(v0, v1);                    // 3 VALU

        // B1: groups 0,1 both carry [d_eh, d_l, d_el, 0]
        S8 B1;
        B1.i[0] = bact ? ehl.x : 0;
        B1.i[1] = bact ? d_l   : 0;
        B1.i[2] = bact ? ehl.y : 0;
        B1.i[3] = 0;

        // GEMM1: 4 MFMAs (A 2-term packed along K), bias in C
        f32x4 h1[4];
        #pragma unroll
        for (int mt = 0; mt < 4; ++mt)
            h1[mt] = MFMA(A1[mt].h, B1.h, b1c[mt]);
        #pragma unroll
        for (int mt = 0; mt < 4; ++mt) {
            h1[mt][0] = fmaxf(h1[mt][0], 0.f);
            h1[mt][1] = fmaxf(h1[mt][1], 0.f);
            h1[mt][2] = fmaxf(h1[mt][2], 0.f);
            h1[mt][3] = fmaxf(h1[mt][3], 0.f);
        }

        // B2 frags: 1-term f16, same sigma1 D->k alignment as verified r3/r4
        S8 B20, B21;
        B20.i[0] = pack_f16(h1[0][0], h1[0][1]);
        B20.i[1] = pack_f16(h1[0][2], h1[0][3]);
        B20.i[2] = pack_f16(h1[1][0], h1[1][1]);
        B20.i[3] = pack_f16(h1[1][2], h1[1][3]);
        B21.i[0] = pack_f16(h1[2][0], h1[2][1]);
        B21.i[1] = pack_f16(h1[2][2], h1[2][3]);
        B21.i[2] = pack_f16(h1[3][0], h1[3][1]);
        B21.i[3] = pack_f16(h1[3][2], h1[3][3]);

        // GEMM2: 8 MFMAs (Ah+Al per kt), bias in C
        f32x4 h2[2];
        #pragma unroll
        for (int mt2 = 0; mt2 < 2; ++mt2) {
            f32x4 acc = b2c[mt2];
            acc = MFMA(A2H[mt2].h,     B20.h, acc);
            acc = MFMA(A2L[mt2].h,     B20.h, acc);
            acc = MFMA(A2H[2 + mt2].h, B21.h, acc);
            acc = MFMA(A2L[2 + mt2].h, B21.h, acc);
            h2[mt2] = acc;
        }
        #pragma unroll
        for (int mt2 = 0; mt2 < 2; ++mt2) {
            h2[mt2][0] = fmaxf(h2[mt2][0], 0.f);
            h2[mt2][1] = fmaxf(h2[mt2][1], 0.f);
            h2[mt2][2] = fmaxf(h2[mt2][2], 0.f);
            h2[mt2][3] = fmaxf(h2[mt2][3], 0.f);
        }

        // B3 frag: 1-term f16
        S8 B3;
        B3.i[0] = pack_f16(h2[0][0], h2[0][1]);
        B3.i[1] = pack_f16(h2[0][2], h2[0][3]);
        B3.i[2] = pack_f16(h2[1][0], h2[1][1]);
        B3.i[3] = pack_f16(h2[1][2], h2[1][3]);

        // GEMM3: 2 MFMAs, bias in C
        f32x4 h3 = MFMA(A3H.h, B3.h, b3c);
        h3 = MFMA(A3L.h, B3.h, h3);

        #pragma unroll
        for (int r = 0; r < 4; ++r) {
            rs[r] += h3[r];
            rm[r] = fmaxf(rm[r], h3[r]);
        }

        fa = nfa; v0 = nv0; v1 = nv1;
    }

    // ---- reduce over the 16 position-lanes within each 16-lane group ----
    #pragma unroll
    for (int off = 1; off <= 8; off <<= 1) {
        #pragma unroll
        for (int r = 0; r < 4; ++r) {
            rs[r] += __shfl_xor(rs[r], off);
            rm[r] = fmaxf(rm[r], __shfl_xor(rm[r], off));
        }
    }
    if (L == 0) {
        #pragma unroll
        for (int r = 0; r < 4; ++r) {
            int m = 4 * g + r;
            if (m < 5) { redS[wid][m] = rs[r]; redM[wid][m] = rm[r]; }
        }
    }
    __syncthreads();

    // ---- combine 4 waves + build hh[14] ----
    if (t < 5) {
        hhs[t] = (redS[0][t] + redS[1][t]) + (redS[2][t] + redS[3][t]);
    } else if (t < 10) {
        int m = t - 5;
        hhs[t] = fmaxf(fmaxf(redM[0][m], redM[1][m]), fmaxf(redM[2][m], redM[3][m]));
    } else if (t == 10) {
        int xa = (int)x_features[b * 3];
        hhs[10] = embr[2 * xa];
        hhs[11] = embr[2 * xa + 1];
        hhs[12] = x_features[b * 3 + 1];
        hhs[13] = x_features[b * 3 + 2];
    }
    __syncthreads();

    // ---- head MLP: 14 -> 50 -> 25 -> 1 (weights direct from L2) ----
    if (t < 50) {
        float acc = rb1[t];
        #pragma unroll
        for (int i = 0; i < 14; ++i) acc += hhs[i] * rW1[i * 50 + t];
        r1buf[t] = fmaxf(acc, 0.f);
    }
    __syncthreads();

    float oacc = 0.f;
    if (t < 25) {
        float acc = rb2[t];
        #pragma unroll
        for (int k = 0; k < 50; ++k) acc += r1buf[k] * rW2[k * 25 + t];
        oacc = fmaxf(acc, 0.f) * rW3[t];
    }
    if (t < 64) {
        #pragma unroll
        for (int off = 32; off > 0; off >>= 1) oacc += __shfl_down(oacc, off);
        if (t == 0) out[b] = oacc + rb3[0];
    }
}

extern "C" void kernel_launch(void* const* d_in, const int* in_sizes, int n_in,
                              void* d_out, int out_size, void* d_ws, size_t ws_size,
                              hipStream_t stream) {
    const float* x_features = (const float*)d_in[0];
    const float* features   = (const float*)d_in[1];
    // d_in[2] = lengths (dead in the math)
    const float* emb = (const float*)d_in[3];
    const float* fW1 = (const float*)d_in[4];
    const float* fb1 = (const float*)d_in[5];
    const float* fW2 = (const float*)d_in[6];
    const float* fb2 = (const float*)d_in[7];
    const float* fW3 = (const float*)d_in[8];
    const float* fb3 = (const float*)d_in[9];
    const float* rW1 = (const float*)d_in[10];
    const float* rb1 = (const float*)d_in[11];
    const float* rW2 = (const float*)d_in[12];
    const float* rb2 = (const float*)d_in[13];
    const float* rW3 = (const float*)d_in[14];
    const float* rb3 = (const float*)d_in[15];
    float* out = (float*)d_out;
    int* ws = (int*)d_ws;

    sp_prep<<<1, 64, 0, stream>>>(emb, fW1, fb1, fW2, fb2, fW3, fb3, ws);
    sp_main<<<BSZ, 256, 0, stream>>>(x_features, features, ws,
                                     rW1, rb1, rW2, rb2, rW3, rb3, out);
}

// Round 9
// 85.105 us; speedup vs baseline: 1.3732x; 1.0098x over previous
//
#include <hip/hip_runtime.h>
#include <stdint.h>

#define BSZ 4096
#define LSEQ 1024

typedef _Float16 half8 __attribute__((ext_vector_type(8)));
typedef float f32x4 __attribute__((ext_vector_type(4)));

union S8 { int i[4]; half8 h; int4 q; };

__device__ __forceinline__ int pack_f16(float a, float b) {
    union { _Float16 h[2]; int i; } u;
    u.h[0] = (_Float16)a;          // v_cvt_f16_f32 (RNE)
    u.h[1] = (_Float16)b;
    return u.i;                    // v_pack_b32_f16
}
// (a,b) -> hi dword [f16(b)|f16(a)], lo dword [f16(b-bh)|f16(a-ah)]
__device__ __forceinline__ void split_pair_f16(float a, float b, int& dh, int& dl) {
    _Float16 ah = (_Float16)a, bh = (_Float16)b;
    float al = a - (float)ah, bl = b - (float)bh;
    union { _Float16 h[2]; int i; } uh, ul;
    uh.h[0] = ah; uh.h[1] = bh;
    ul.h[0] = (_Float16)al; ul.h[1] = (_Float16)bl;
    dh = uh.i; dl = ul.i;
}
__device__ __forceinline__ f32x4 MFMA(half8 a, half8 b, f32x4 c) {
    return __builtin_amdgcn_mfma_f32_16x16x32_f16(a, b, c, 0, 0, 0);
}

// ws layout (int units):
//   int4 slots 0..13   : A fragments [f][lane]   (14*64*4 = 3584 ints)
//   f32x4 slots 14..17 : bias1 C-frags [mt][lane]
//   f32x4 slots 18..19 : bias2 C-frags [mt2][lane]
//   f32x4 slot  20     : bias3 C-frag  [lane]
//   WS_EMBH + app      : embedding hi dword (f16 e0,e1)
//   WS_EMBL + app      : embedding lo dword
//   WS_EMBR + i        : raw normalized embedding floats [10][2]
#define WS_EMBH 5376
#define WS_EMBL 5392
#define WS_EMBR 5408

__global__ void sp_prep(const float* __restrict__ emb,
                        const float* __restrict__ fW1, const float* __restrict__ fb1,
                        const float* __restrict__ fW2, const float* __restrict__ fb2,
                        const float* __restrict__ fW3, const float* __restrict__ fb3,
                        int* __restrict__ ws)
{
    const int lane = threadIdx.x;          // 64 threads, 1 wave
    const int L = lane & 15, g = lane >> 4;
    int4* wf = (int4*)ws;
    f32x4* bp = (f32x4*)ws;

    // ---- A1: one frag per mt; A 2-term f16 packed along K ----
    // B1 supplies (all lanes): [d_eh, d_l, d_el, 0]; A zero for g>=2 masks k>=16.
    #pragma unroll
    for (int mt = 0; mt < 4; ++mt) {
        int j1 = ((mt >> 1) << 5) + ((L >> 2) << 3) + ((mt & 1) << 2) + (L & 3);
        float wv[4];
        _Float16 ah[4]; float alv[4];
        #pragma unroll
        for (int c = 0; c < 4; ++c) {
            wv[c] = (j1 < 50) ? fW1[c * 50 + j1] : 0.f;
            ah[c] = (_Float16)wv[c];
            alv[c] = wv[c] - (float)ah[c];
        }
        _Float16 v[8];
        #pragma unroll
        for (int e = 0; e < 8; ++e) {
            _Float16 x = (_Float16)0.f;
            if (g == 0) {
                if (e < 4) x = ah[e];
                else if (e < 6) x = ah[e - 4];
            } else if (g == 1) {
                if (e < 4) x = (_Float16)alv[e];
                else if (e < 6) x = (_Float16)alv[e - 4];
            }
            v[e] = x;
        }
        S8 F;
        #pragma unroll
        for (int d = 0; d < 4; ++d) {
            union { _Float16 h[2]; int i; } u;
            u.h[0] = v[2 * d]; u.h[1] = v[2 * d + 1];
            F.i[d] = u.i;
        }
        wf[mt * 64 + lane] = F.q;
    }

    // ---- A2 Ah/Al frags (sigma2 row permutation; f16 2-term) ----
    #pragma unroll
    for (int kt = 0; kt < 2; ++kt) {
        #pragma unroll
        for (int mt2 = 0; mt2 < 2; ++mt2) {
            int j2 = ((L >> 2) << 3) + (mt2 << 2) + (L & 3);
            float w[8];
            #pragma unroll
            for (int r = 0; r < 8; ++r) {
                int j1v = kt * 32 + 8 * g + r;
                w[r] = (j1v < 50 && j2 < 25) ? fW2[j1v * 25 + j2] : 0.f;
            }
            S8 H, Lo;
            #pragma unroll
            for (int d = 0; d < 4; ++d) split_pair_f16(w[2*d], w[2*d+1], H.i[d], Lo.i[d]);
            wf[(4 + kt * 2 + mt2) * 64 + lane] = H.q;
            wf[(8 + kt * 2 + mt2) * 64 + lane] = Lo.q;
        }
    }

    // ---- A3 Ah/Al frags ----
    {
        int m = L;
        float w[8];
        #pragma unroll
        for (int r = 0; r < 8; ++r) {
            int j2v = 8 * g + r;
            w[r] = (j2v < 25 && m < 5) ? fW3[j2v * 5 + m] : 0.f;
        }
        S8 H, Lo;
        #pragma unroll
        for (int d = 0; d < 4; ++d) split_pair_f16(w[2*d], w[2*d+1], H.i[d], Lo.i[d]);
        wf[12 * 64 + lane] = H.q;
        wf[13 * 64 + lane] = Lo.q;
    }

    // ---- bias C-fragments (C/D row = 4g+r, col = L) ----
    #pragma unroll
    for (int mt = 0; mt < 4; ++mt) {
        f32x4 bv;
        #pragma unroll
        for (int r = 0; r < 4; ++r) {
            int j1 = ((mt >> 1) << 5) + 8 * g + ((mt & 1) << 2) + r;
            bv[r] = (j1 < 50) ? fb1[j1] : 0.f;
        }
        bp[(14 + mt) * 64 + lane] = bv;
    }
    #pragma unroll
    for (int mt2 = 0; mt2 < 2; ++mt2) {
        f32x4 bv;
        #pragma unroll
        for (int r = 0; r < 4; ++r) {
            int j2 = 8 * g + 4 * mt2 + r;
            bv[r] = (j2 < 25) ? fb2[j2] : 0.f;
        }
        bp[(18 + mt2) * 64 + lane] = bv;
    }
    {
        f32x4 bv;
        #pragma unroll
        for (int r = 0; r < 4; ++r) {
            int m = 4 * g + r;
            bv[r] = (m < 5) ? fb3[m] : 0.f;
        }
        bp[20 * 64 + lane] = bv;
    }

    // ---- renormalized embedding: raw floats + f16 hi/lo dwords ----
    if (lane < 10) {
        float a0 = emb[2 * lane], a1 = emb[2 * lane + 1];
        float n = sqrtf(a0 * a0 + a1 * a1);
        float s = fminf(1.f, 1.f / fmaxf(n, 1e-7f));
        float e0 = a0 * s, e1 = a1 * s;
        int dh, dl;
        split_pair_f16(e0, e1, dh, dl);
        ws[WS_EMBH + lane] = dh;
        ws[WS_EMBL + lane] = dl;
        ((float*)ws)[WS_EMBR + 2 * lane] = e0;
        ((float*)ws)[WS_EMBR + 2 * lane + 1] = e1;
    }
}

__global__ __launch_bounds__(256, 4) void sp_main(
    const float* __restrict__ x_features,
    const float* __restrict__ features,
    const int* __restrict__ ws,
    const float* __restrict__ rW1, const float* __restrict__ rb1,
    const float* __restrict__ rW2, const float* __restrict__ rb2,
    const float* __restrict__ rW3, const float* __restrict__ rb3,
    float* __restrict__ out)
{
    __shared__ int2 embhl[16];
    __shared__ float embr[20];
    __shared__ float redS[4][5], redM[4][5];
    __shared__ float hhs[14];
    __shared__ float r1buf[50];

    const int t = threadIdx.x;
    const int b = blockIdx.x;
    const int lane = t & 63;
    const int wid = t >> 6;
    const int L = lane & 15;

    // ---- load prepacked A fragments + bias C-frags (L2-broadcast) ----
    const int4* wf = (const int4*)ws;
    const f32x4* bp = (const f32x4*)ws;
    S8 A1[4], A2H[4], A2L[4], A3H, A3L;
    #pragma unroll
    for (int f = 0; f < 4; ++f)  A1[f].q  = wf[f * 64 + lane];
    #pragma unroll
    for (int f = 0; f < 4; ++f)  A2H[f].q = wf[(4 + f) * 64 + lane];
    #pragma unroll
    for (int f = 0; f < 4; ++f)  A2L[f].q = wf[(8 + f) * 64 + lane];
    A3H.q = wf[12 * 64 + lane];
    A3L.q = wf[13 * 64 + lane];
    f32x4 b1c[4], b2c[2], b3c;
    #pragma unroll
    for (int f = 0; f < 4; ++f) b1c[f] = bp[(14 + f) * 64 + lane];
    b2c[0] = bp[18 * 64 + lane];
    b2c[1] = bp[19 * 64 + lane];
    b3c = bp[20 * 64 + lane];

    if (t < 16) { embhl[t] = make_int2(ws[WS_EMBH + t], ws[WS_EMBL + t]); }
    if (t < 20) embr[t] = ((const float*)ws)[WS_EMBR + t];
    __syncthreads();

    const float* f0 = features + (size_t)b * (3 * LSEQ);
    const float* pa = f0;
    const float* pb = f0 + LSEQ;
    const float* pc = f0 + 2 * LSEQ;
    const int lbase = wid * 256 + L;

    float rs[4] = {0.f, 0.f, 0.f, 0.f};
    float rm[4] = {-3.4e38f, -3.4e38f, -3.4e38f, -3.4e38f};

    // software-pipelined input stream (prefetch next tile's 3 floats)
    float fa = pa[lbase], v0 = pb[lbase], v1 = pc[lbase];

    #pragma unroll 2
    for (int it = 0; it < 16; ++it) {
        const int ln = lbase + ((it + 1) & 15) * 16;   // wraps on last iter (in-bounds)
        float nfa = pa[ln], nv0 = pb[ln], nv1 = pc[ln];

        int app = (int)fa;
        int2 ehl = embhl[app];                         // one ds_read_b64
        int d_l = pack_f16(v0, v1);                    // 3 VALU

        // B1 (all lanes identical; A zeros for g>=2 mask those k exactly)
        S8 B1;
        B1.i[0] = ehl.x;
        B1.i[1] = d_l;
        B1.i[2] = ehl.y;
        B1.i[3] = 0;

        // GEMM1: 4 MFMAs (A 2-term packed along K), bias in C
        f32x4 h1[4];
        #pragma unroll
        for (int mt = 0; mt < 4; ++mt)
            h1[mt] = MFMA(A1[mt].h, B1.h, b1c[mt]);
        #pragma unroll
        for (int mt = 0; mt < 4; ++mt) {
            h1[mt][0] = fmaxf(h1[mt][0], 0.f);
            h1[mt][1] = fmaxf(h1[mt][1], 0.f);
            h1[mt][2] = fmaxf(h1[mt][2], 0.f);
            h1[mt][3] = fmaxf(h1[mt][3], 0.f);
        }

        // B2 frags: 1-term f16, same sigma1 D->k alignment as verified r3/r4/r7
        S8 B20, B21;
        B20.i[0] = pack_f16(h1[0][0], h1[0][1]);
        B20.i[1] = pack_f16(h1[0][2], h1[0][3]);
        B20.i[2] = pack_f16(h1[1][0], h1[1][1]);
        B20.i[3] = pack_f16(h1[1][2], h1[1][3]);
        B21.i[0] = pack_f16(h1[2][0], h1[2][1]);
        B21.i[1] = pack_f16(h1[2][2], h1[2][3]);
        B21.i[2] = pack_f16(h1[3][0], h1[3][1]);
        B21.i[3] = pack_f16(h1[3][2], h1[3][3]);

        // GEMM2: 8 MFMAs (Ah+Al per kt), bias in C
        f32x4 h2[2];
        #pragma unroll
        for (int mt2 = 0; mt2 < 2; ++mt2) {
            f32x4 acc = b2c[mt2];
            acc = MFMA(A2H[mt2].h,     B20.h, acc);
            acc = MFMA(A2L[mt2].h,     B20.h, acc);
            acc = MFMA(A2H[2 + mt2].h, B21.h, acc);
            acc = MFMA(A2L[2 + mt2].h, B21.h, acc);
            h2[mt2] = acc;
        }
        #pragma unroll
        for (int mt2 = 0; mt2 < 2; ++mt2) {
            h2[mt2][0] = fmaxf(h2[mt2][0], 0.f);
            h2[mt2][1] = fmaxf(h2[mt2][1], 0.f);
            h2[mt2][2] = fmaxf(h2[mt2][2], 0.f);
            h2[mt2][3] = fmaxf(h2[mt2][3], 0.f);
        }

        // B3 frag: 1-term f16
        S8 B3;
        B3.i[0] = pack_f16(h2[0][0], h2[0][1]);
        B3.i[1] = pack_f16(h2[0][2], h2[0][3]);
        B3.i[2] = pack_f16(h2[1][0], h2[1][1]);
        B3.i[3] = pack_f16(h2[1][2], h2[1][3]);

        // GEMM3: 2 MFMAs, bias in C
        f32x4 h3 = MFMA(A3H.h, B3.h, b3c);
        h3 = MFMA(A3L.h, B3.h, h3);

        #pragma unroll
        for (int r = 0; r < 4; ++r) {
            rs[r] += h3[r];
            rm[r] = fmaxf(rm[r], h3[r]);
        }

        fa = nfa; v0 = nv0; v1 = nv1;
    }

    // ---- reduce over the 16 position-lanes within each 16-lane group ----
    #pragma unroll
    for (int off = 1; off <= 8; off <<= 1) {
        #pragma unroll
        for (int r = 0; r < 4; ++r) {
            rs[r] += __shfl_xor(rs[r], off);
            rm[r] = fmaxf(rm[r], __shfl_xor(rm[r], off));
        }
    }
    {
        const int kg = (lane >> 4);
        if (L == 0) {
            #pragma unroll
            for (int r = 0; r < 4; ++r) {
                int m = 4 * kg + r;
                if (m < 5) { redS[wid][m] = rs[r]; redM[wid][m] = rm[r]; }
            }
        }
    }
    __syncthreads();

    // ---- combine 4 waves + build hh[14] ----
    if (t < 5) {
        hhs[t] = (redS[0][t] + redS[1][t]) + (redS[2][t] + redS[3][t]);
    } else if (t < 10) {
        int m = t - 5;
        hhs[t] = fmaxf(fmaxf(redM[0][m], redM[1][m]), fmaxf(redM[2][m], redM[3][m]));
    } else if (t == 10) {
        int xa = (int)x_features[b * 3];
        hhs[10] = embr[2 * xa];
        hhs[11] = embr[2 * xa + 1];
        hhs[12] = x_features[b * 3 + 1];
        hhs[13] = x_features[b * 3 + 2];
    }
    __syncthreads();

    // ---- head MLP: 14 -> 50 -> 25 -> 1 (weights direct from L2) ----
    if (t < 50) {
        float acc = rb1[t];
        #pragma unroll
        for (int i = 0; i < 14; ++i) acc += hhs[i] * rW1[i * 50 + t];
        r1buf[t] = fmaxf(acc, 0.f);
    }
    __syncthreads();

    float oacc = 0.f;
    if (t < 25) {
        float acc = rb2[t];
        #pragma unroll
        for (int k = 0; k < 50; ++k) acc += r1buf[k] * rW2[k * 25 + t];
        oacc = fmaxf(acc, 0.f) * rW3[t];
    }
    if (t < 64) {
        #pragma unroll
        for (int off = 32; off > 0; off >>= 1) oacc += __shfl_down(oacc, off);
        if (t == 0) out[b] = oacc + rb3[0];
    }
}

extern "C" void kernel_launch(void* const* d_in, const int* in_sizes, int n_in,
                              void* d_out, int out_size, void* d_ws, size_t ws_size,
                              hipStream_t stream) {
    const float* x_features = (const float*)d_in[0];
    const float* features   = (const float*)d_in[1];
    // d_in[2] = lengths (dead in the math)
    const float* emb = (const float*)d_in[3];
    const float* fW1 = (const float*)d_in[4];
    const float* fb1 = (const float*)d_in[5];
    const float* fW2 = (const float*)d_in[6];
    const float* fb2 = (const float*)d_in[7];
    const float* fW3 = (const float*)d_in[8];
    const float* fb3 = (const float*)d_in[9];
    const float* rW1 = (const float*)d_in[10];
    const float* rb1 = (const float*)d_in[11];
    const float* rW2 = (const float*)d_in[12];
    const float* rb2 = (const float*)d_in[13];
    const float* rW3 = (const float*)d_in[14];
    const float* rb3 = (const float*)d_in[15];
    float* out = (float*)d_out;
    int* ws = (int*)d_ws;

    sp_prep<<<1, 64, 0, stream>>>(emb, fW1, fb1, fW2, fb2, fW3, fb3, ws);
    sp_main<<<BSZ, 256, 0, stream>>>(x_features, features, ws,
                                     rW1, rb1, rW2, rb2, rW3, rb3, out);
}

// Round 10
// 74.480 us; speedup vs baseline: 1.5691x; 1.1427x over previous
//
#include <hip/hip_runtime.h>
#include <stdint.h>

#define BSZ 4096
#define LSEQ 1024

typedef _Float16 half8 __attribute__((ext_vector_type(8)));
typedef float f32x4 __attribute__((ext_vector_type(4)));

union S8 { int i[4]; half8 h; int4 q; };

__device__ __forceinline__ int pack_f16(float a, float b) {
    union { _Float16 h[2]; int i; } u;
    u.h[0] = (_Float16)a;          // v_cvt_f16_f32 (RNE)
    u.h[1] = (_Float16)b;
    return u.i;                    // v_pack_b32_f16
}
// (a,b) -> hi dword [f16(b)|f16(a)], lo dword [f16(b-bh)|f16(a-ah)]
__device__ __forceinline__ void split_pair_f16(float a, float b, int& dh, int& dl) {
    _Float16 ah = (_Float16)a, bh = (_Float16)b;
    float al = a - (float)ah, bl = b - (float)bh;
    union { _Float16 h[2]; int i; } uh, ul;
    uh.h[0] = ah; uh.h[1] = bh;
    ul.h[0] = (_Float16)al; ul.h[1] = (_Float16)bl;
    dh = uh.i; dl = ul.i;
}
__device__ __forceinline__ f32x4 MFMA(half8 a, half8 b, f32x4 c) {
    return __builtin_amdgcn_mfma_f32_16x16x32_f16(a, b, c, 0, 0, 0);
}

// ws layout (int units):
//   int4 slots 0..13   : A fragments [f][lane]   (14*64*4 = 3584 ints)
//   f32x4 slots 14..17 : bias1 C-frags [mt][lane]
//   f32x4 slots 18..19 : bias2 C-frags [mt2][lane]
//   f32x4 slot  20     : bias3 C-frag  [lane]
//   WS_EMBH + app      : embedding hi dword (f16 e0,e1)
//   WS_EMBL + app      : embedding lo dword
//   WS_EMBR + i        : raw normalized embedding floats [10][2]
#define WS_EMBH 5376
#define WS_EMBL 5392
#define WS_EMBR 5408

__global__ void sp_prep(const float* __restrict__ emb,
                        const float* __restrict__ fW1, const float* __restrict__ fb1,
                        const float* __restrict__ fW2, const float* __restrict__ fb2,
                        const float* __restrict__ fW3, const float* __restrict__ fb3,
                        int* __restrict__ ws)
{
    const int lane = threadIdx.x;          // 64 threads, 1 wave
    const int L = lane & 15, g = lane >> 4;
    int4* wf = (int4*)ws;
    f32x4* bp = (f32x4*)ws;

    // ---- A1: one frag per mt; A 2-term f16 packed along K ----
    // B1 supplies (all lanes): [d_eh, d_l, d_el, 0]; A zero for g>=2 masks k>=16.
    #pragma unroll
    for (int mt = 0; mt < 4; ++mt) {
        int j1 = ((mt >> 1) << 5) + ((L >> 2) << 3) + ((mt & 1) << 2) + (L & 3);
        float wv[4];
        _Float16 ah[4]; float alv[4];
        #pragma unroll
        for (int c = 0; c < 4; ++c) {
            wv[c] = (j1 < 50) ? fW1[c * 50 + j1] : 0.f;
            ah[c] = (_Float16)wv[c];
            alv[c] = wv[c] - (float)ah[c];
        }
        _Float16 v[8];
        #pragma unroll
        for (int e = 0; e < 8; ++e) {
            _Float16 x = (_Float16)0.f;
            if (g == 0) {
                if (e < 4) x = ah[e];
                else if (e < 6) x = ah[e - 4];
            } else if (g == 1) {
                if (e < 4) x = (_Float16)alv[e];
                else if (e < 6) x = (_Float16)alv[e - 4];
            }
            v[e] = x;
        }
        S8 F;
        #pragma unroll
        for (int d = 0; d < 4; ++d) {
            union { _Float16 h[2]; int i; } u;
            u.h[0] = v[2 * d]; u.h[1] = v[2 * d + 1];
            F.i[d] = u.i;
        }
        wf[mt * 64 + lane] = F.q;
    }

    // ---- A2 Ah/Al frags (sigma2 row permutation; f16 2-term) ----
    #pragma unroll
    for (int kt = 0; kt < 2; ++kt) {
        #pragma unroll
        for (int mt2 = 0; mt2 < 2; ++mt2) {
            int j2 = ((L >> 2) << 3) + (mt2 << 2) + (L & 3);
            float w[8];
            #pragma unroll
            for (int r = 0; r < 8; ++r) {
                int j1v = kt * 32 + 8 * g + r;
                w[r] = (j1v < 50 && j2 < 25) ? fW2[j1v * 25 + j2] : 0.f;
            }
            S8 H, Lo;
            #pragma unroll
            for (int d = 0; d < 4; ++d) split_pair_f16(w[2*d], w[2*d+1], H.i[d], Lo.i[d]);
            wf[(4 + kt * 2 + mt2) * 64 + lane] = H.q;
            wf[(8 + kt * 2 + mt2) * 64 + lane] = Lo.q;
        }
    }

    // ---- A3 Ah/Al frags ----
    {
        int m = L;
        float w[8];
        #pragma unroll
        for (int r = 0; r < 8; ++r) {
            int j2v = 8 * g + r;
            w[r] = (j2v < 25 && m < 5) ? fW3[j2v * 5 + m] : 0.f;
        }
        S8 H, Lo;
        #pragma unroll
        for (int d = 0; d < 4; ++d) split_pair_f16(w[2*d], w[2*d+1], H.i[d], Lo.i[d]);
        wf[12 * 64 + lane] = H.q;
        wf[13 * 64 + lane] = Lo.q;
    }

    // ---- bias C-fragments (C/D row = 4g+r, col = L) ----
    #pragma unroll
    for (int mt = 0; mt < 4; ++mt) {
        f32x4 bv;
        #pragma unroll
        for (int r = 0; r < 4; ++r) {
            int j1 = ((mt >> 1) << 5) + 8 * g + ((mt & 1) << 2) + r;
            bv[r] = (j1 < 50) ? fb1[j1] : 0.f;
        }
        bp[(14 + mt) * 64 + lane] = bv;
    }
    #pragma unroll
    for (int mt2 = 0; mt2 < 2; ++mt2) {
        f32x4 bv;
        #pragma unroll
        for (int r = 0; r < 4; ++r) {
            int j2 = 8 * g + 4 * mt2 + r;
            bv[r] = (j2 < 25) ? fb2[j2] : 0.f;
        }
        bp[(18 + mt2) * 64 + lane] = bv;
    }
    {
        f32x4 bv;
        #pragma unroll
        for (int r = 0; r < 4; ++r) {
            int m = 4 * g + r;
            bv[r] = (m < 5) ? fb3[m] : 0.f;
        }
        bp[20 * 64 + lane] = bv;
    }

    // ---- renormalized embedding: raw floats + f16 hi/lo dwords ----
    if (lane < 10) {
        float a0 = emb[2 * lane], a1 = emb[2 * lane + 1];
        float n = sqrtf(a0 * a0 + a1 * a1);
        float s = fminf(1.f, 1.f / fmaxf(n, 1e-7f));
        float e0 = a0 * s, e1 = a1 * s;
        int dh, dl;
        split_pair_f16(e0, e1, dh, dl);
        ws[WS_EMBH + lane] = dh;
        ws[WS_EMBL + lane] = dl;
        ((float*)ws)[WS_EMBR + 2 * lane] = e0;
        ((float*)ws)[WS_EMBR + 2 * lane + 1] = e1;
    }
}

__global__ __launch_bounds__(256, 4) void sp_main(
    const float* __restrict__ x_features,
    const float* __restrict__ features,
    const int* __restrict__ ws,
    const float* __restrict__ rW1, const float* __restrict__ rb1,
    const float* __restrict__ rW2, const float* __restrict__ rb2,
    const float* __restrict__ rW3, const float* __restrict__ rb3,
    float* __restrict__ out)
{
    __shared__ int2 embhl[16];
    __shared__ float embr[20];
    __shared__ int2 eh[LSEQ];      // per-position embedding (hi,lo) packed f16 dwords
    __shared__ int  pl[LSEQ];      // per-position packed f16 (l0,l1)
    __shared__ float redS[4][5], redM[4][5];
    __shared__ float hhs[14];
    __shared__ float r1buf[50];

    const int t = threadIdx.x;
    const int b = blockIdx.x;
    const int lane = t & 63;
    const int wid = t >> 6;
    const int L = lane & 15;

    // ---- load prepacked A fragments + bias C-frags (L2-broadcast) ----
    const int4* wf = (const int4*)ws;
    const f32x4* bp = (const f32x4*)ws;
    S8 A1[4], A2H[4], A2L[4], A3H, A3L;
    #pragma unroll
    for (int f = 0; f < 4; ++f)  A1[f].q  = wf[f * 64 + lane];
    #pragma unroll
    for (int f = 0; f < 4; ++f)  A2H[f].q = wf[(4 + f) * 64 + lane];
    #pragma unroll
    for (int f = 0; f < 4; ++f)  A2L[f].q = wf[(8 + f) * 64 + lane];
    A3H.q = wf[12 * 64 + lane];
    A3L.q = wf[13 * 64 + lane];
    f32x4 b1c[4], b2c[2], b3c;
    #pragma unroll
    for (int f = 0; f < 4; ++f) b1c[f] = bp[(14 + f) * 64 + lane];
    b2c[0] = bp[18 * 64 + lane];
    b2c[1] = bp[19 * 64 + lane];
    b3c = bp[20 * 64 + lane];

    if (t < 16) { embhl[t] = make_int2(ws[WS_EMBH + t], ws[WS_EMBL + t]); }
    if (t < 20) embr[t] = ((const float*)ws)[WS_EMBR + t];
    __syncthreads();

    // ---- stage the block's 3 input rows into LDS, pre-gathered/packed ----
    // positions 4t..4t+3 per thread; rows are contiguous in `features`.
    const float* f0 = features + (size_t)b * (3 * LSEQ);
    {
        const float4* ra = (const float4*)(f0);             // app row
        const float4* rb = (const float4*)(f0 + LSEQ);      // l0 row
        const float4* rc = (const float4*)(f0 + 2 * LSEQ);  // l1 row
        float4 a4 = ra[t], b4 = rb[t], c4 = rc[t];
        int2 e0 = embhl[(int)a4.x];
        int2 e1 = embhl[(int)a4.y];
        int2 e2 = embhl[(int)a4.z];
        int2 e3 = embhl[(int)a4.w];
        int4 p4;
        p4.x = pack_f16(b4.x, c4.x);
        p4.y = pack_f16(b4.y, c4.y);
        p4.z = pack_f16(b4.z, c4.z);
        p4.w = pack_f16(b4.w, c4.w);
        *(int4*)(pl + 4 * t) = p4;
        int4 eA, eB;
        eA.x = e0.x; eA.y = e0.y; eA.z = e1.x; eA.w = e1.y;
        eB.x = e2.x; eB.y = e2.y; eB.z = e3.x; eB.w = e3.y;
        *(int4*)(eh + 4 * t)     = eA;
        *(int4*)(eh + 4 * t + 2) = eB;
    }
    __syncthreads();

    float rs[4] = {0.f, 0.f, 0.f, 0.f};
    float rm[4] = {-3.4e38f, -3.4e38f, -3.4e38f, -3.4e38f};

    const int lbase = wid * 256 + L;

    #pragma unroll 2
    for (int it = 0; it < 16; ++it) {
        const int l = lbase + it * 16;
        int2 ehl = eh[l];              // ds_read_b64 (broadcast in 16-groups)
        int d_l = pl[l];               // ds_read_b32

        // B1 (all lanes identical; A zeros for g>=2 mask those k exactly)
        S8 B1;
        B1.i[0] = ehl.x;
        B1.i[1] = d_l;
        B1.i[2] = ehl.y;
        B1.i[3] = 0;

        // GEMM1: 4 MFMAs (A 2-term packed along K), bias in C
        f32x4 h1[4];
        #pragma unroll
        for (int mt = 0; mt < 4; ++mt)
            h1[mt] = MFMA(A1[mt].h, B1.h, b1c[mt]);
        #pragma unroll
        for (int mt = 0; mt < 4; ++mt) {
            h1[mt][0] = fmaxf(h1[mt][0], 0.f);
            h1[mt][1] = fmaxf(h1[mt][1], 0.f);
            h1[mt][2] = fmaxf(h1[mt][2], 0.f);
            h1[mt][3] = fmaxf(h1[mt][3], 0.f);
        }

        // B2 frags: 1-term f16, same sigma1 D->k alignment as verified r3/r4/r7
        S8 B20, B21;
        B20.i[0] = pack_f16(h1[0][0], h1[0][1]);
        B20.i[1] = pack_f16(h1[0][2], h1[0][3]);
        B20.i[2] = pack_f16(h1[1][0], h1[1][1]);
        B20.i[3] = pack_f16(h1[1][2], h1[1][3]);
        B21.i[0] = pack_f16(h1[2][0], h1[2][1]);
        B21.i[1] = pack_f16(h1[2][2], h1[2][3]);
        B21.i[2] = pack_f16(h1[3][0], h1[3][1]);
        B21.i[3] = pack_f16(h1[3][2], h1[3][3]);

        // GEMM2: 8 MFMAs (Ah+Al per kt), bias in C
        f32x4 h2[2];
        #pragma unroll
        for (int mt2 = 0; mt2 < 2; ++mt2) {
            f32x4 acc = b2c[mt2];
            acc = MFMA(A2H[mt2].h,     B20.h, acc);
            acc = MFMA(A2L[mt2].h,     B20.h, acc);
            acc = MFMA(A2H[2 + mt2].h, B21.h, acc);
            acc = MFMA(A2L[2 + mt2].h, B21.h, acc);
            h2[mt2] = acc;
        }
        #pragma unroll
        for (int mt2 = 0; mt2 < 2; ++mt2) {
            h2[mt2][0] = fmaxf(h2[mt2][0], 0.f);
            h2[mt2][1] = fmaxf(h2[mt2][1], 0.f);
            h2[mt2][2] = fmaxf(h2[mt2][2], 0.f);
            h2[mt2][3] = fmaxf(h2[mt2][3], 0.f);
        }

        // B3 frag: 1-term f16
        S8 B3;
        B3.i[0] = pack_f16(h2[0][0], h2[0][1]);
        B3.i[1] = pack_f16(h2[0][2], h2[0][3]);
        B3.i[2] = pack_f16(h2[1][0], h2[1][1]);
        B3.i[3] = pack_f16(h2[1][2], h2[1][3]);

        // GEMM3: 2 MFMAs, bias in C
        f32x4 h3 = MFMA(A3H.h, B3.h, b3c);
        h3 = MFMA(A3L.h, B3.h, h3);

        #pragma unroll
        for (int r = 0; r < 4; ++r) {
            rs[r] += h3[r];
            rm[r] = fmaxf(rm[r], h3[r]);
        }
    }

    // ---- reduce over the 16 position-lanes within each 16-lane group ----
    #pragma unroll
    for (int off = 1; off <= 8; off <<= 1) {
        #pragma unroll
        for (int r = 0; r < 4; ++r) {
            rs[r] += __shfl_xor(rs[r], off);
            rm[r] = fmaxf(rm[r], __shfl_xor(rm[r], off));
        }
    }
    {
        const int kg = (lane >> 4);
        if (L == 0) {
            #pragma unroll
            for (int r = 0; r < 4; ++r) {
                int m = 4 * kg + r;
                if (m < 5) { redS[wid][m] = rs[r]; redM[wid][m] = rm[r]; }
            }
        }
    }
    __syncthreads();

    // ---- combine 4 waves + build hh[14] ----
    if (t < 5) {
        hhs[t] = (redS[0][t] + redS[1][t]) + (redS[2][t] + redS[3][t]);
    } else if (t < 10) {
        int m = t - 5;
        hhs[t] = fmaxf(fmaxf(redM[0][m], redM[1][m]), fmaxf(redM[2][m], redM[3][m]));
    } else if (t == 10) {
        int xa = (int)x_features[b * 3];
        hhs[10] = embr[2 * xa];
        hhs[11] = embr[2 * xa + 1];
        hhs[12] = x_features[b * 3 + 1];
        hhs[13] = x_features[b * 3 + 2];
    }
    __syncthreads();

    // ---- head MLP: 14 -> 50 -> 25 -> 1 (weights direct from L2) ----
    if (t < 50) {
        float acc = rb1[t];
        #pragma unroll
        for (int i = 0; i < 14; ++i) acc += hhs[i] * rW1[i * 50 + t];
        r1buf[t] = fmaxf(acc, 0.f);
    }
    __syncthreads();

    float oacc = 0.f;
    if (t < 25) {
        float acc = rb2[t];
        #pragma unroll
        for (int k = 0; k < 50; ++k) acc += r1buf[k] * rW2[k * 25 + t];
        oacc = fmaxf(acc, 0.f) * rW3[t];
    }
    if (t < 64) {
        #pragma unroll
        for (int off = 32; off > 0; off >>= 1) oacc += __shfl_down(oacc, off);
        if (t == 0) out[b] = oacc + rb3[0];
    }
}

extern "C" void kernel_launch(void* const* d_in, const int* in_sizes, int n_in,
                              void* d_out, int out_size, void* d_ws, size_t ws_size,
                              hipStream_t stream) {
    const float* x_features = (const float*)d_in[0];
    const float* features   = (const float*)d_in[1];
    // d_in[2] = lengths (dead in the math)
    const float* emb = (const float*)d_in[3];
    const float* fW1 = (const float*)d_in[4];
    const float* fb1 = (const float*)d_in[5];
    const float* fW2 = (const float*)d_in[6];
    const float* fb2 = (const float*)d_in[7];
    const float* fW3 = (const float*)d_in[8];
    const float* fb3 = (const float*)d_in[9];
    const float* rW1 = (const float*)d_in[10];
    const float* rb1 = (const float*)d_in[11];
    const float* rW2 = (const float*)d_in[12];
    const float* rb2 = (const float*)d_in[13];
    const float* rW3 = (const float*)d_in[14];
    const float* rb3 = (const float*)d_in[15];
    float* out = (float*)d_out;
    int* ws = (int*)d_ws;

    sp_prep<<<1, 64, 0, stream>>>(emb, fW1, fb1, fW2, fb2, fW3, fb3, ws);
    sp_main<<<BSZ, 256, 0, stream>>>(x_features, features, ws,
                                     rW1, rb1, rW2, rb2, rW3, rb3, out);
}

// Round 12
// 65.596 us; speedup vs baseline: 1.7816x; 1.1354x over previous
//
#include <hip/hip_runtime.h>
#include <stdint.h>

#define BSZ 4096
#define LSEQ 1024

typedef _Float16 half8 __attribute__((ext_vector_type(8)));
typedef __fp16 fp16x2 __attribute__((ext_vector_type(2)));
typedef float f32x4 __attribute__((ext_vector_type(4)));

union S8 { int i[4]; half8 h; int4 q; };

__device__ __forceinline__ int pack_f16(float a, float b) {
    union { _Float16 h[2]; int i; } u;
    u.h[0] = (_Float16)a;          // v_cvt_f16_f32 (RNE)
    u.h[1] = (_Float16)b;
    return u.i;                    // v_pack_b32_f16
}
// relu + RTZ pack: one v_cvt_pkrtz_f16_f32 after two f32 fmax
__device__ __forceinline__ int relu_pkrtz(float a, float b) {
    union { fp16x2 h; int i; } u;
    u.h = __builtin_amdgcn_cvt_pkrtz(fmaxf(a, 0.f), fmaxf(b, 0.f));
    return u.i;
}
// (a,b) -> hi dword [f16(b)|f16(a)], lo dword [f16(b-bh)|f16(a-ah)]
__device__ __forceinline__ void split_pair_f16(float a, float b, int& dh, int& dl) {
    _Float16 ah = (_Float16)a, bh = (_Float16)b;
    float al = a - (float)ah, bl = b - (float)bh;
    union { _Float16 h[2]; int i; } uh, ul;
    uh.h[0] = ah; uh.h[1] = bh;
    ul.h[0] = (_Float16)al; ul.h[1] = (_Float16)bl;
    dh = uh.i; dl = ul.i;
}
__device__ __forceinline__ f32x4 MFMA(half8 a, half8 b, f32x4 c) {
    return __builtin_amdgcn_mfma_f32_16x16x32_f16(a, b, c, 0, 0, 0);
}

// ws layout (int units):
//   int4 slots 0..13   : A fragments [f][lane]   (14*64*4 = 3584 ints)
//   f32x4 slots 14..17 : bias1 C-frags [mt][lane]
//   f32x4 slots 18..19 : bias2 C-frags [mt2][lane]
//   f32x4 slot  20     : bias3 C-frag  [lane]
//   WS_EMBH + app      : embedding hi dword (f16 e0,e1)
//   WS_EMBL + app      : embedding lo dword
//   WS_EMBR + i        : raw normalized embedding floats [10][2]
#define WS_EMBH 5376
#define WS_EMBL 5392
#define WS_EMBR 5408

__global__ void sp_prep(const float* __restrict__ emb,
                        const float* __restrict__ fW1, const float* __restrict__ fb1,
                        const float* __restrict__ fW2, const float* __restrict__ fb2,
                        const float* __restrict__ fW3, const float* __restrict__ fb3,
                        int* __restrict__ ws)
{
    const int lane = threadIdx.x;          // 64 threads, 1 wave
    const int L = lane & 15, g = lane >> 4;
    int4* wf = (int4*)ws;
    f32x4* bp = (f32x4*)ws;

    // ---- A1: one frag per mt; A 2-term f16 packed along K ----
    // B1 supplies (all lanes): [d_eh, d_l, d_el, 0]; A zero for g>=2 masks k>=16.
    #pragma unroll
    for (int mt = 0; mt < 4; ++mt) {
        int j1 = ((mt >> 1) << 5) + ((L >> 2) << 3) + ((mt & 1) << 2) + (L & 3);
        float wv[4];
        _Float16 ah[4]; float alv[4];
        #pragma unroll
        for (int c = 0; c < 4; ++c) {
            wv[c] = (j1 < 50) ? fW1[c * 50 + j1] : 0.f;
            ah[c] = (_Float16)wv[c];
            alv[c] = wv[c] - (float)ah[c];
        }
        _Float16 v[8];
        #pragma unroll
        for (int e = 0; e < 8; ++e) {
            _Float16 x = (_Float16)0.f;
            if (g == 0) {
                if (e < 4) x = ah[e];
                else if (e < 6) x = ah[e - 4];
            } else if (g == 1) {
                if (e < 4) x = (_Float16)alv[e];
                else if (e < 6) x = (_Float16)alv[e - 4];
            }
            v[e] = x;
        }
        S8 F;
        #pragma unroll
        for (int d = 0; d < 4; ++d) {
            union { _Float16 h[2]; int i; } u;
            u.h[0] = v[2 * d]; u.h[1] = v[2 * d + 1];
            F.i[d] = u.i;
        }
        wf[mt * 64 + lane] = F.q;
    }

    // ---- A2 Ah/Al frags (sigma2 row permutation; f16 2-term) ----
    #pragma unroll
    for (int kt = 0; kt < 2; ++kt) {
        #pragma unroll
        for (int mt2 = 0; mt2 < 2; ++mt2) {
            int j2 = ((L >> 2) << 3) + (mt2 << 2) + (L & 3);
            float w[8];
            #pragma unroll
            for (int r = 0; r < 8; ++r) {
                int j1v = kt * 32 + 8 * g + r;
                w[r] = (j1v < 50 && j2 < 25) ? fW2[j1v * 25 + j2] : 0.f;
            }
            S8 H, Lo;
            #pragma unroll
            for (int d = 0; d < 4; ++d) split_pair_f16(w[2*d], w[2*d+1], H.i[d], Lo.i[d]);
            wf[(4 + kt * 2 + mt2) * 64 + lane] = H.q;
            wf[(8 + kt * 2 + mt2) * 64 + lane] = Lo.q;
        }
    }

    // ---- A3 Ah/Al frags ----
    {
        int m = L;
        float w[8];
        #pragma unroll
        for (int r = 0; r < 8; ++r) {
            int j2v = 8 * g + r;
            w[r] = (j2v < 25 && m < 5) ? fW3[j2v * 5 + m] : 0.f;
        }
        S8 H, Lo;
        #pragma unroll
        for (int d = 0; d < 4; ++d) split_pair_f16(w[2*d], w[2*d+1], H.i[d], Lo.i[d]);
        wf[12 * 64 + lane] = H.q;
        wf[13 * 64 + lane] = Lo.q;
    }

    // ---- bias C-fragments (C/D row = 4g+r, col = L) ----
    #pragma unroll
    for (int mt = 0; mt < 4; ++mt) {
        f32x4 bv;
        #pragma unroll
        for (int r = 0; r < 4; ++r) {
            int j1 = ((mt >> 1) << 5) + 8 * g + ((mt & 1) << 2) + r;
            bv[r] = (j1 < 50) ? fb1[j1] : 0.f;
        }
        bp[(14 + mt) * 64 + lane] = bv;
    }
    #pragma unroll
    for (int mt2 = 0; mt2 < 2; ++mt2) {
        f32x4 bv;
        #pragma unroll
        for (int r = 0; r < 4; ++r) {
            int j2 = 8 * g + 4 * mt2 + r;
            bv[r] = (j2 < 25) ? fb2[j2] : 0.f;
        }
        bp[(18 + mt2) * 64 + lane] = bv;
    }
    {
        f32x4 bv;
        #pragma unroll
        for (int r = 0; r < 4; ++r) {
            int m = 4 * g + r;
            bv[r] = (m < 5) ? fb3[m] : 0.f;
        }
        bp[20 * 64 + lane] = bv;
    }

    // ---- renormalized embedding: raw floats + f16 hi/lo dwords ----
    if (lane < 10) {
        float a0 = emb[2 * lane], a1 = emb[2 * lane + 1];
        float n = sqrtf(a0 * a0 + a1 * a1);
        float s = fminf(1.f, 1.f / fmaxf(n, 1e-7f));
        float e0 = a0 * s, e1 = a1 * s;
        int dh, dl;
        split_pair_f16(e0, e1, dh, dl);
        ws[WS_EMBH + lane] = dh;
        ws[WS_EMBL + lane] = dl;
        ((float*)ws)[WS_EMBR + 2 * lane] = e0;
        ((float*)ws)[WS_EMBR + 2 * lane + 1] = e1;
    }
}

__global__ __launch_bounds__(256, 4) void sp_main(
    const float* __restrict__ x_features,
    const float* __restrict__ features,
    const int* __restrict__ ws,
    const float* __restrict__ rW1, const float* __restrict__ rb1,
    const float* __restrict__ rW2, const float* __restrict__ rb2,
    const float* __restrict__ rW3, const float* __restrict__ rb3,
    float* __restrict__ out)
{
    __shared__ int2 embhl[16];
    __shared__ float embr[20];
    __shared__ int4 bseq[LSEQ + 4];   // staged B1 frags, idx = p + (p>>8) bank-stagger
    __shared__ float redS[4][5], redM[4][5];
    __shared__ float hhs[14];
    __shared__ float r1buf[50];

    const int t = threadIdx.x;
    const int b = blockIdx.x;
    const int lane = t & 63;
    const int wid = t >> 6;
    const int L = lane & 15;

    // ---- load prepacked A fragments + bias C-frags (L2-broadcast) ----
    const int4* wf = (const int4*)ws;
    const f32x4* bp = (const f32x4*)ws;
    S8 A1[4], A2H[4], A2L[4], A3H, A3L;
    #pragma unroll
    for (int f = 0; f < 4; ++f)  A1[f].q  = wf[f * 64 + lane];
    #pragma unroll
    for (int f = 0; f < 4; ++f)  A2H[f].q = wf[(4 + f) * 64 + lane];
    #pragma unroll
    for (int f = 0; f < 4; ++f)  A2L[f].q = wf[(8 + f) * 64 + lane];
    A3H.q = wf[12 * 64 + lane];
    A3L.q = wf[13 * 64 + lane];
    f32x4 b1c[4], b2c[2], b3c;
    #pragma unroll
    for (int f = 0; f < 4; ++f) b1c[f] = bp[(14 + f) * 64 + lane];
    b2c[0] = bp[18 * 64 + lane];
    b2c[1] = bp[19 * 64 + lane];
    b3c = bp[20 * 64 + lane];

    if (t < 16) { embhl[t] = make_int2(ws[WS_EMBH + t], ws[WS_EMBL + t]); }
    if (t < 20) embr[t] = ((const float*)ws)[WS_EMBR + t];
    __syncthreads();

    // ---- stage the block's inputs as ready-to-use B1 int4 frags ----
    // thread t handles positions 4t..4t+3 (coalesced float4 global reads)
    const float* f0 = features + (size_t)b * (3 * LSEQ);
    {
        const float4* ra = (const float4*)(f0);             // app row
        const float4* rb = (const float4*)(f0 + LSEQ);      // l0 row
        const float4* rc = (const float4*)(f0 + 2 * LSEQ);  // l1 row
        float4 a4 = ra[t], b4 = rb[t], c4 = rc[t];
        int2 e0 = embhl[(int)a4.x];
        int2 e1 = embhl[(int)a4.y];
        int2 e2 = embhl[(int)a4.z];
        int2 e3 = embhl[(int)a4.w];
        const int base = 4 * t + (t >> 6);   // p + (p>>8), constant across j
        bseq[base + 0] = make_int4(e0.x, pack_f16(b4.x, c4.x), e0.y, 0);
        bseq[base + 1] = make_int4(e1.x, pack_f16(b4.y, c4.y), e1.y, 0);
        bseq[base + 2] = make_int4(e2.x, pack_f16(b4.z, c4.z), e2.y, 0);
        bseq[base + 3] = make_int4(e3.x, pack_f16(b4.w, c4.w), e3.y, 0);
    }
    __syncthreads();

    float rs[4] = {0.f, 0.f, 0.f, 0.f};
    float rm[4] = {-3.4e38f, -3.4e38f, -3.4e38f, -3.4e38f};

    const int lbase = wid * 257 + L;        // includes +wid bank-stagger

    #pragma unroll 2
    for (int it = 0; it < 16; ++it) {
        S8 B1;
        B1.q = bseq[lbase + it * 16];       // one ds_read_b128, conflict-free

        // GEMM1: 4 MFMAs (A 2-term packed along K), bias in C
        f32x4 h1[4];
        #pragma unroll
        for (int mt = 0; mt < 4; ++mt)
            h1[mt] = MFMA(A1[mt].h, B1.h, b1c[mt]);

        // B2 frags: relu + RTZ pack (3 ops/dword), sigma1 D->k alignment
        S8 B20, B21;
        B20.i[0] = relu_pkrtz(h1[0][0], h1[0][1]);
        B20.i[1] = relu_pkrtz(h1[0][2], h1[0][3]);
        B20.i[2] = relu_pkrtz(h1[1][0], h1[1][1]);
        B20.i[3] = relu_pkrtz(h1[1][2], h1[1][3]);
        B21.i[0] = relu_pkrtz(h1[2][0], h1[2][1]);
        B21.i[1] = relu_pkrtz(h1[2][2], h1[2][3]);
        B21.i[2] = relu_pkrtz(h1[3][0], h1[3][1]);
        B21.i[3] = relu_pkrtz(h1[3][2], h1[3][3]);

        // GEMM2: 8 MFMAs (Ah+Al per kt), bias in C
        f32x4 h2[2];
        #pragma unroll
        for (int mt2 = 0; mt2 < 2; ++mt2) {
            f32x4 acc = b2c[mt2];
            acc = MFMA(A2H[mt2].h,     B20.h, acc);
            acc = MFMA(A2L[mt2].h,     B20.h, acc);
            acc = MFMA(A2H[2 + mt2].h, B21.h, acc);
            acc = MFMA(A2L[2 + mt2].h, B21.h, acc);
            h2[mt2] = acc;
        }

        // B3 frag: relu + RTZ pack
        S8 B3;
        B3.i[0] = relu_pkrtz(h2[0][0], h2[0][1]);
        B3.i[1] = relu_pkrtz(h2[0][2], h2[0][3]);
        B3.i[2] = relu_pkrtz(h2[1][0], h2[1][1]);
        B3.i[3] = relu_pkrtz(h2[1][2], h2[1][3]);

        // GEMM3: 2 MFMAs, bias in C
        f32x4 h3 = MFMA(A3H.h, B3.h, b3c);
        h3 = MFMA(A3L.h, B3.h, h3);

        #pragma unroll
        for (int r = 0; r < 4; ++r) {
            rs[r] += h3[r];
            rm[r] = fmaxf(rm[r], h3[r]);
        }
    }

    // ---- reduce over the 16 position-lanes within each 16-lane group ----
    #pragma unroll
    for (int off = 1; off <= 8; off <<= 1) {
        #pragma unroll
        for (int r = 0; r < 4; ++r) {
            rs[r] += __shfl_xor(rs[r], off);
            rm[r] = fmaxf(rm[r], __shfl_xor(rm[r], off));
        }
    }
    {
        const int kg = (lane >> 4);
        if (L == 0) {
            #pragma unroll
            for (int r = 0; r < 4; ++r) {
                int m = 4 * kg + r;
                if (m < 5) { redS[wid][m] = rs[r]; redM[wid][m] = rm[r]; }
            }
        }
    }
    __syncthreads();

    // ---- combine 4 waves + build hh[14] ----
    if (t < 5) {
        hhs[t] = (redS[0][t] + redS[1][t]) + (redS[2][t] + redS[3][t]);
    } else if (t < 10) {
        int m = t - 5;
        hhs[t] = fmaxf(fmaxf(redM[0][m], redM[1][m]), fmaxf(redM[2][m], redM[3][m]));
    } else if (t == 10) {
        int xa = (int)x_features[b * 3];
        hhs[10] = embr[2 * xa];
        hhs[11] = embr[2 * xa + 1];
        hhs[12] = x_features[b * 3 + 1];
        hhs[13] = x_features[b * 3 + 2];
    }
    __syncthreads();

    // ---- head MLP: 14 -> 50 -> 25 -> 1 (weights direct from L2) ----
    if (t < 50) {
        float acc = rb1[t];
        #pragma unroll
        for (int i = 0; i < 14; ++i) acc += hhs[i] * rW1[i * 50 + t];
        r1buf[t] = fmaxf(acc, 0.f);
    }
    __syncthreads();

    float oacc = 0.f;
    if (t < 25) {
        float acc = rb2[t];
        #pragma unroll
        for (int k = 0; k < 50; ++k) acc += r1buf[k] * rW2[k * 25 + t];
        oacc = fmaxf(acc, 0.f) * rW3[t];
    }
    if (t < 64) {
        #pragma unroll
        for (int off = 32; off > 0; off >>= 1) oacc += __shfl_down(oacc, off);
        if (t == 0) out[b] = oacc + rb3[0];
    }
}

extern "C" void kernel_launch(void* const* d_in, const int* in_sizes, int n_in,
                              void* d_out, int out_size, void* d_ws, size_t ws_size,
                              hipStream_t stream) {
    const float* x_features = (const float*)d_in[0];
    const float* features   = (const float*)d_in[1];
    // d_in[2] = lengths (dead in the math)
    const float* emb = (const float*)d_in[3];
    const float* fW1 = (const float*)d_in[4];
    const float* fb1 = (const float*)d_in[5];
    const float* fW2 = (const float*)d_in[6];
    const float* fb2 = (const float*)d_in[7];
    const float* fW3 = (const float*)d_in[8];
    const float* fb3 = (const float*)d_in[9];
    const float* rW1 = (const float*)d_in[10];
    const float* rb1 = (const float*)d_in[11];
    const float* rW2 = (const float*)d_in[12];
    const float* rb2 = (const float*)d_in[13];
    const float* rW3 = (const float*)d_in[14];
    const float* rb3 = (const float*)d_in[15];
    float* out = (float*)d_out;
    int* ws = (int*)d_ws;

    sp_prep<<<1, 64, 0, stream>>>(emb, fW1, fb1, fW2, fb2, fW3, fb3, ws);
    sp_main<<<BSZ, 256, 0, stream>>>(x_features, features, ws,
                                     rW1, rb1, rW2, rb2, rW3, rb3, out);
}

// Round 13
// 55.672 us; speedup vs baseline: 2.0992x; 1.1783x over previous
//
#include <hip/hip_runtime.h>
#include <stdint.h>

#define BSZ 4096
#define LSEQ 1024

typedef _Float16 half8 __attribute__((ext_vector_type(8)));
typedef __fp16 fp16x2 __attribute__((ext_vector_type(2)));
typedef float f32x4 __attribute__((ext_vector_type(4)));

union S8 { int i[4]; half8 h; int4 q; };

__device__ __forceinline__ int pack_f16(float a, float b) {
    union { _Float16 h[2]; int i; } u;
    u.h[0] = (_Float16)a;          // v_cvt_f16_f32 (RNE)
    u.h[1] = (_Float16)b;
    return u.i;                    // v_pack_b32_f16
}
// RTZ pack then packed f16 relu: v_cvt_pkrtz_f16_f32 + v_pk_max_f16 (2 VALU)
__device__ __forceinline__ int relu_pkrtz(float a, float b) {
    fp16x2 h = __builtin_amdgcn_cvt_pkrtz(a, b);
    h = __builtin_elementwise_max(h, (fp16x2)0.f);
    union { fp16x2 v; int i; } u;
    u.v = h;
    return u.i;
}
// (a,b) -> hi dword [f16(b)|f16(a)], lo dword [f16(b-bh)|f16(a-ah)]
__device__ __forceinline__ void split_pair_f16(float a, float b, int& dh, int& dl) {
    _Float16 ah = (_Float16)a, bh = (_Float16)b;
    float al = a - (float)ah, bl = b - (float)bh;
    union { _Float16 h[2]; int i; } uh, ul;
    uh.h[0] = ah; uh.h[1] = bh;
    ul.h[0] = (_Float16)al; ul.h[1] = (_Float16)bl;
    dh = uh.i; dl = ul.i;
}
__device__ __forceinline__ f32x4 MFMA(half8 a, half8 b, f32x4 c) {
    return __builtin_amdgcn_mfma_f32_16x16x32_f16(a, b, c, 0, 0, 0);
}

// ws layout (int units):
//   int4 slots 0..13   : A fragments [f][lane]   (14*64*4 = 3584 ints)
//   f32x4 slots 14..17 : bias1 C-frags [mt][lane]
//   f32x4 slots 18..19 : bias2 C-frags [mt2][lane]
//   f32x4 slot  20     : bias3 C-frag  [lane]
//   WS_EMBH + app      : embedding hi dword (f16 e0,e1)
//   WS_EMBL + app      : embedding lo dword
//   WS_EMBR + i        : raw normalized embedding floats [10][2]
#define WS_EMBH 5376
#define WS_EMBL 5392
#define WS_EMBR 5408

__global__ void sp_prep(const float* __restrict__ emb,
                        const float* __restrict__ fW1, const float* __restrict__ fb1,
                        const float* __restrict__ fW2, const float* __restrict__ fb2,
                        const float* __restrict__ fW3, const float* __restrict__ fb3,
                        int* __restrict__ ws)
{
    const int lane = threadIdx.x;          // 64 threads, 1 wave
    const int L = lane & 15, g = lane >> 4;
    int4* wf = (int4*)ws;
    f32x4* bp = (f32x4*)ws;

    // ---- A1: one frag per mt; A 2-term f16 packed along K ----
    // B1 supplies (all lanes): [d_eh, d_l, d_el, 0]; A zero for g>=2 masks k>=16.
    #pragma unroll
    for (int mt = 0; mt < 4; ++mt) {
        int j1 = ((mt >> 1) << 5) + ((L >> 2) << 3) + ((mt & 1) << 2) + (L & 3);
        float wv[4];
        _Float16 ah[4]; float alv[4];
        #pragma unroll
        for (int c = 0; c < 4; ++c) {
            wv[c] = (j1 < 50) ? fW1[c * 50 + j1] : 0.f;
            ah[c] = (_Float16)wv[c];
            alv[c] = wv[c] - (float)ah[c];
        }
        _Float16 v[8];
        #pragma unroll
        for (int e = 0; e < 8; ++e) {
            _Float16 x = (_Float16)0.f;
            if (g == 0) {
                if (e < 4) x = ah[e];
                else if (e < 6) x = ah[e - 4];
            } else if (g == 1) {
                if (e < 4) x = (_Float16)alv[e];
                else if (e < 6) x = (_Float16)alv[e - 4];
            }
            v[e] = x;
        }
        S8 F;
        #pragma unroll
        for (int d = 0; d < 4; ++d) {
            union { _Float16 h[2]; int i; } u;
            u.h[0] = v[2 * d]; u.h[1] = v[2 * d + 1];
            F.i[d] = u.i;
        }
        wf[mt * 64 + lane] = F.q;
    }

    // ---- A2 Ah/Al frags (sigma2 row permutation; f16 2-term) ----
    #pragma unroll
    for (int kt = 0; kt < 2; ++kt) {
        #pragma unroll
        for (int mt2 = 0; mt2 < 2; ++mt2) {
            int j2 = ((L >> 2) << 3) + (mt2 << 2) + (L & 3);
            float w[8];
            #pragma unroll
            for (int r = 0; r < 8; ++r) {
                int j1v = kt * 32 + 8 * g + r;
                w[r] = (j1v < 50 && j2 < 25) ? fW2[j1v * 25 + j2] : 0.f;
            }
            S8 H, Lo;
            #pragma unroll
            for (int d = 0; d < 4; ++d) split_pair_f16(w[2*d], w[2*d+1], H.i[d], Lo.i[d]);
            wf[(4 + kt * 2 + mt2) * 64 + lane] = H.q;
            wf[(8 + kt * 2 + mt2) * 64 + lane] = Lo.q;
        }
    }

    // ---- A3 Ah/Al frags ----
    {
        int m = L;
        float w[8];
        #pragma unroll
        for (int r = 0; r < 8; ++r) {
            int j2v = 8 * g + r;
            w[r] = (j2v < 25 && m < 5) ? fW3[j2v * 5 + m] : 0.f;
        }
        S8 H, Lo;
        #pragma unroll
        for (int d = 0; d < 4; ++d) split_pair_f16(w[2*d], w[2*d+1], H.i[d], Lo.i[d]);
        wf[12 * 64 + lane] = H.q;
        wf[13 * 64 + lane] = Lo.q;
    }

    // ---- bias C-fragments (C/D row = 4g+r, col = L) ----
    #pragma unroll
    for (int mt = 0; mt < 4; ++mt) {
        f32x4 bv;
        #pragma unroll
        for (int r = 0; r < 4; ++r) {
            int j1 = ((mt >> 1) << 5) + 8 * g + ((mt & 1) << 2) + r;
            bv[r] = (j1 < 50) ? fb1[j1] : 0.f;
        }
        bp[(14 + mt) * 64 + lane] = bv;
    }
    #pragma unroll
    for (int mt2 = 0; mt2 < 2; ++mt2) {
        f32x4 bv;
        #pragma unroll
        for (int r = 0; r < 4; ++r) {
            int j2 = 8 * g + 4 * mt2 + r;
            bv[r] = (j2 < 25) ? fb2[j2] : 0.f;
        }
        bp[(18 + mt2) * 64 + lane] = bv;
    }
    {
        f32x4 bv;
        #pragma unroll
        for (int r = 0; r < 4; ++r) {
            int m = 4 * g + r;
            bv[r] = (m < 5) ? fb3[m] : 0.f;
        }
        bp[20 * 64 + lane] = bv;
    }

    // ---- renormalized embedding: raw floats + f16 hi/lo dwords ----
    if (lane < 10) {
        float a0 = emb[2 * lane], a1 = emb[2 * lane + 1];
        float n = sqrtf(a0 * a0 + a1 * a1);
        float s = fminf(1.f, 1.f / fmaxf(n, 1e-7f));
        float e0 = a0 * s, e1 = a1 * s;
        int dh, dl;
        split_pair_f16(e0, e1, dh, dl);
        ws[WS_EMBH + lane] = dh;
        ws[WS_EMBL + lane] = dl;
        ((float*)ws)[WS_EMBR + 2 * lane] = e0;
        ((float*)ws)[WS_EMBR + 2 * lane + 1] = e1;
    }
}

__global__ __launch_bounds__(256, 4) void sp_main(
    const float* __restrict__ x_features,
    const float* __restrict__ features,
    const int* __restrict__ ws,
    const float* __restrict__ rW1, const float* __restrict__ rb1,
    const float* __restrict__ rW2, const float* __restrict__ rb2,
    const float* __restrict__ rW3, const float* __restrict__ rb3,
    float* __restrict__ out)
{
    __shared__ int2 embhl[16];
    __shared__ float embr[20];
    __shared__ int4 bseq[LSEQ + 4];   // staged B1 frags, idx = p + (p>>8) bank-stagger
    __shared__ float redS[4][5], redM[4][5];
    __shared__ float hhs[14];
    __shared__ float r1buf[50];

    const int t = threadIdx.x;
    const int b = blockIdx.x;
    const int lane = t & 63;
    const int wid = t >> 6;
    const int L = lane & 15;

    // ---- load prepacked A fragments + bias C-frags (L2-broadcast) ----
    const int4* wf = (const int4*)ws;
    const f32x4* bp = (const f32x4*)ws;
    S8 A1[4], A2H[4], A2L[4], A3H, A3L;
    #pragma unroll
    for (int f = 0; f < 4; ++f)  A1[f].q  = wf[f * 64 + lane];
    #pragma unroll
    for (int f = 0; f < 4; ++f)  A2H[f].q = wf[(4 + f) * 64 + lane];
    #pragma unroll
    for (int f = 0; f < 4; ++f)  A2L[f].q = wf[(8 + f) * 64 + lane];
    A3H.q = wf[12 * 64 + lane];
    A3L.q = wf[13 * 64 + lane];
    f32x4 b1c[4], b2c[2], b3c;
    #pragma unroll
    for (int f = 0; f < 4; ++f) b1c[f] = bp[(14 + f) * 64 + lane];
    b2c[0] = bp[18 * 64 + lane];
    b2c[1] = bp[19 * 64 + lane];
    b3c = bp[20 * 64 + lane];

    if (t < 16) { embhl[t] = make_int2(ws[WS_EMBH + t], ws[WS_EMBL + t]); }
    if (t < 20) embr[t] = ((const float*)ws)[WS_EMBR + t];
    __syncthreads();

    // ---- stage the block's inputs as ready-to-use B1 int4 frags ----
    // thread t handles positions {t, t+256, t+512, t+768}: scalar loads stay
    // coalesced (256B/instr) and ds_write_b128 lane-stride is 16B -> conflict-free.
    const float* f0 = features + (size_t)b * (3 * LSEQ);
    #pragma unroll
    for (int j = 0; j < 4; ++j) {
        const int p = t + 256 * j;
        float av = f0[p];
        float bv = f0[LSEQ + p];
        float cv = f0[2 * LSEQ + p];
        int2 e = embhl[(int)av];
        bseq[p + j] = make_int4(e.x, pack_f16(bv, cv), e.y, 0);   // p>>8 == j
    }
    __syncthreads();

    float rs[4] = {0.f, 0.f, 0.f, 0.f};
    float rm[4] = {-3.4e38f, -3.4e38f, -3.4e38f, -3.4e38f};

    const int lbase = wid * 257 + L;        // includes +wid bank-stagger

    // register prefetch of B1 (one ds_read_b128 ahead)
    S8 B1c;
    B1c.q = bseq[lbase];

    #pragma unroll 2
    for (int it = 0; it < 16; ++it) {
        S8 B1n;
        B1n.q = bseq[lbase + ((it + 1) & 15) * 16];   // wraps on last iter

        // GEMM1: 4 MFMAs (A 2-term packed along K), bias in C
        f32x4 h1[4];
        #pragma unroll
        for (int mt = 0; mt < 4; ++mt)
            h1[mt] = MFMA(A1[mt].h, B1c.h, b1c[mt]);

        // B2 frags: RTZ pack + packed relu (2 ops/dword), sigma1 D->k alignment
        S8 B20, B21;
        B20.i[0] = relu_pkrtz(h1[0][0], h1[0][1]);
        B20.i[1] = relu_pkrtz(h1[0][2], h1[0][3]);
        B20.i[2] = relu_pkrtz(h1[1][0], h1[1][1]);
        B20.i[3] = relu_pkrtz(h1[1][2], h1[1][3]);
        B21.i[0] = relu_pkrtz(h1[2][0], h1[2][1]);
        B21.i[1] = relu_pkrtz(h1[2][2], h1[2][3]);
        B21.i[2] = relu_pkrtz(h1[3][0], h1[3][1]);
        B21.i[3] = relu_pkrtz(h1[3][2], h1[3][3]);

        // GEMM2: 8 MFMAs (Ah+Al per kt), bias in C
        f32x4 h2[2];
        #pragma unroll
        for (int mt2 = 0; mt2 < 2; ++mt2) {
            f32x4 acc = b2c[mt2];
            acc = MFMA(A2H[mt2].h,     B20.h, acc);
            acc = MFMA(A2L[mt2].h,     B20.h, acc);
            acc = MFMA(A2H[2 + mt2].h, B21.h, acc);
            acc = MFMA(A2L[2 + mt2].h, B21.h, acc);
            h2[mt2] = acc;
        }

        // B3 frag: RTZ pack + packed relu
        S8 B3;
        B3.i[0] = relu_pkrtz(h2[0][0], h2[0][1]);
        B3.i[1] = relu_pkrtz(h2[0][2], h2[0][3]);
        B3.i[2] = relu_pkrtz(h2[1][0], h2[1][1]);
        B3.i[3] = relu_pkrtz(h2[1][2], h2[1][3]);

        // GEMM3: 2 MFMAs, bias in C
        f32x4 h3 = MFMA(A3H.h, B3.h, b3c);
        h3 = MFMA(A3L.h, B3.h, h3);

        #pragma unroll
        for (int r = 0; r < 4; ++r) {
            rs[r] += h3[r];
            rm[r] = fmaxf(rm[r], h3[r]);
        }

        B1c = B1n;
    }

    // ---- reduce over the 16 position-lanes within each 16-lane group ----
    #pragma unroll
    for (int off = 1; off <= 8; off <<= 1) {
        #pragma unroll
        for (int r = 0; r < 4; ++r) {
            rs[r] += __shfl_xor(rs[r], off);
            rm[r] = fmaxf(rm[r], __shfl_xor(rm[r], off));
        }
    }
    {
        const int kg = (lane >> 4);
        if (L == 0) {
            #pragma unroll
            for (int r = 0; r < 4; ++r) {
                int m = 4 * kg + r;
                if (m < 5) { redS[wid][m] = rs[r]; redM[wid][m] = rm[r]; }
            }
        }
    }
    __syncthreads();

    // ---- combine 4 waves + build hh[14] ----
    if (t < 5) {
        hhs[t] = (redS[0][t] + redS[1][t]) + (redS[2][t] + redS[3][t]);
    } else if (t < 10) {
        int m = t - 5;
        hhs[t] = fmaxf(fmaxf(redM[0][m], redM[1][m]), fmaxf(redM[2][m], redM[3][m]));
    } else if (t == 10) {
        int xa = (int)x_features[b * 3];
        hhs[10] = embr[2 * xa];
        hhs[11] = embr[2 * xa + 1];
        hhs[12] = x_features[b * 3 + 1];
        hhs[13] = x_features[b * 3 + 2];
    }
    __syncthreads();

    // ---- head MLP: 14 -> 50 -> 25 -> 1 (weights direct from L2) ----
    if (t < 50) {
        float acc = rb1[t];
        #pragma unroll
        for (int i = 0; i < 14; ++i) acc += hhs[i] * rW1[i * 50 + t];
        r1buf[t] = fmaxf(acc, 0.f);
    }
    __syncthreads();

    float oacc = 0.f;
    if (t < 25) {
        float acc = rb2[t];
        #pragma unroll
        for (int k = 0; k < 50; ++k) acc += r1buf[k] * rW2[k * 25 + t];
        oacc = fmaxf(acc, 0.f) * rW3[t];
    }
    if (t < 64) {
        #pragma unroll
        for (int off = 32; off > 0; off >>= 1) oacc += __shfl_down(oacc, off);
        if (t == 0) out[b] = oacc + rb3[0];
    }
}

extern "C" void kernel_launch(void* const* d_in, const int* in_sizes, int n_in,
                              void* d_out, int out_size, void* d_ws, size_t ws_size,
                              hipStream_t stream) {
    const float* x_features = (const float*)d_in[0];
    const float* features   = (const float*)d_in[1];
    // d_in[2] = lengths (dead in the math)
    const float* emb = (const float*)d_in[3];
    const float* fW1 = (const float*)d_in[4];
    const float* fb1 = (const float*)d_in[5];
    const float* fW2 = (const float*)d_in[6];
    const float* fb2 = (const float*)d_in[7];
    const float* fW3 = (const float*)d_in[8];
    const float* fb3 = (const float*)d_in[9];
    const float* rW1 = (const float*)d_in[10];
    const float* rb1 = (const float*)d_in[11];
    const float* rW2 = (const float*)d_in[12];
    const float* rb2 = (const float*)d_in[13];
    const float* rW3 = (const float*)d_in[14];
    const float* rb3 = (const float*)d_in[15];
    float* out = (float*)d_out;
    int* ws = (int*)d_ws;

    sp_prep<<<1, 64, 0, stream>>>(emb, fW1, fb1, fW2, fb2, fW3, fb3, ws);
    sp_main<<<BSZ, 256, 0, stream>>>(x_features, features, ws,
                                     rW1, rb1, rW2, rb2, rW3, rb3, out);
}